// Round 2
// baseline (380.986 us; speedup 1.0000x reference)
//
#include <hip/hip_runtime.h>
#include <math.h>

#define NN 50000
#define NE 800000
#define NR 16
#define BNODE 64                          // nodes per dst bucket
#define NBC 782                           // ceil(50000/64) buckets
#define ABLK 256                          // blocks in count/scatter passes
#define CHUNK ((NE + ABLK - 1) / ABLK)    // 3125

typedef __attribute__((ext_vector_type(8))) short short8;
typedef __attribute__((ext_vector_type(4))) float floatx4;

__device__ __forceinline__ unsigned short f2bf(float x) {
    unsigned int u = __float_as_uint(x);
    u += 0x7fffu + ((u >> 16) & 1u);
    return (unsigned short)(u >> 16);
}

// ---------------------------------------------------------------------------
// K1 (fused): blocks [0,64): basis MFMA fragments (bf16) + attn frags + aproj
//             blocks [64,260): init_fea = concat(feat, embed[idx]) @ T
//             blocks [260,516): per-chunk coarse dst histogram (dst>>6)
// ---------------------------------------------------------------------------
__global__ void __launch_bounds__(256) k_pre(
    const float* __restrict__ feat, const float* __restrict__ emb,
    const float* __restrict__ T, const int* __restrict__ idx,
    const float* __restrict__ weight, const float* __restrict__ A_w,
    const float* __restrict__ A_b, const float* __restrict__ attn_emb,
    const int* __restrict__ ed,
    float* __restrict__ out, unsigned short* __restrict__ init_bf,
    unsigned short* __restrict__ bfrag, unsigned short* __restrict__ afrag,
    float* __restrict__ aproj, int* __restrict__ cpb) {
    if (blockIdx.x >= 260) {                       // ---- histogram section
        __shared__ int lc[NBC];
        const int cb = blockIdx.x - 260;
        for (int i = threadIdx.x; i < NBC; i += 256) lc[i] = 0;
        __syncthreads();
        const int start = cb * CHUNK, end = min(start + CHUNK, NE);
        for (int e = start + threadIdx.x; e < end; e += 256)
            atomicAdd(&lc[ed[e] >> 6], 1);
        __syncthreads();
        for (int i = threadIdx.x; i < NBC; i += 256) cpb[cb * NBC + i] = lc[i];
        return;
    }
    if (blockIdx.x < 64) {                         // ---- fragment section
        int g = blockIdx.x * 256 + threadIdx.x;    // g < 16384
        if (g < 4 * 2 * 64 * 8) {                  // bfrag: 4096 (1024 per basis)
            int b2 = g >> 10, rest = g & 1023;
            int h = rest >> 9, l = (rest >> 3) & 63, j = rest & 7;
            int k = (l >> 4) * 8 + j, n = (l & 15) + 16 * h;
            bfrag[g] = f2bf(weight[b2 * 1024 + k * 32 + n]);
        }
        if (g < 2 * 2 * 64 * 8) {                  // afrag: 2048 (1024 per ks)
            int ks = g >> 10, rest = g & 1023;
            int nt = rest >> 9, l = (rest >> 3) & 63, j = rest & 7;
            int k = ks * 32 + (l >> 4) * 8 + j, n = (l & 15) + 16 * nt;
            afrag[g] = f2bf(A_w[k * 32 + n]);
        }
        if (g < 16 * 32) {                         // aproj: 512
            int t = g >> 5, j = g & 31;
            float acc = A_b[j];
#pragma unroll
            for (int k = 0; k < 32; k++) acc += attn_emb[t * 32 + k] * A_w[(64 + k) * 32 + j];
            aproj[g] = acc;
        }
        return;
    }
    int i = (blockIdx.x - 64) * 256 + threadIdx.x; // ---- init_fea section
    if (i >= NN) return;
    float v[32], acc[32];
#pragma unroll
    for (int o = 0; o < 32; o++) acc[o] = 0.f;
    const float4* fp = (const float4*)(feat + (size_t)i * 32);
#pragma unroll
    for (int q = 0; q < 8; q++) {
        float4 f = fp[q];
        v[4 * q] = f.x; v[4 * q + 1] = f.y; v[4 * q + 2] = f.z; v[4 * q + 3] = f.w;
    }
#pragma unroll
    for (int d = 0; d < 32; d++) {
        float xd = v[d];
#pragma unroll
        for (int o = 0; o < 32; o++) acc[o] += xd * T[d * 32 + o];
    }
    int row = idx[i];
    const float4* ep = (const float4*)(emb + (size_t)row * 32);
#pragma unroll
    for (int q = 0; q < 8; q++) {
        float4 f = ep[q];
        v[4 * q] = f.x; v[4 * q + 1] = f.y; v[4 * q + 2] = f.z; v[4 * q + 3] = f.w;
    }
#pragma unroll
    for (int d = 0; d < 32; d++) {
        float xd = v[d];
#pragma unroll
        for (int o = 0; o < 32; o++) acc[o] += xd * T[(32 + d) * 32 + o];
    }
    float4* op = (float4*)(out + (size_t)i * 64);
#pragma unroll
    for (int q = 0; q < 8; q++) {
        float4 f;
        f.x = acc[4 * q]; f.y = acc[4 * q + 1]; f.z = acc[4 * q + 2]; f.w = acc[4 * q + 3];
        op[q] = f;
    }
    unsigned int w[16];
#pragma unroll
    for (int q = 0; q < 16; q++)
        w[q] = (unsigned int)f2bf(acc[2 * q]) | ((unsigned int)f2bf(acc[2 * q + 1]) << 16);
    uint4* bp = (uint4*)(init_bf + (size_t)i * 32);
#pragma unroll
    for (int q = 0; q < 4; q++) {
        uint4 u; u.x = w[4 * q]; u.y = w[4 * q + 1]; u.z = w[4 * q + 2]; u.w = w[4 * q + 3];
        bp[q] = u;
    }
}

// ---------------------------------------------------------------------------
// K2: single-block scan of per-chunk bucket counts -> per-chunk cursors (cpbx)
//     and bucket base offsets (boff).
// ---------------------------------------------------------------------------
__global__ void __launch_bounds__(256) k_scanB(const int* __restrict__ cpb,
                                               int* __restrict__ cpbx,
                                               int* __restrict__ boff) {
    __shared__ int tot[NBC];
    for (int bin = threadIdx.x; bin < NBC; bin += 256) {
        int run = 0;
#pragma unroll 8
        for (int c = 0; c < ABLK; c++) {
            int v = cpb[c * NBC + bin];
            cpbx[c * NBC + bin] = run;
            run += v;
        }
        tot[bin] = run;
    }
    __syncthreads();
    if (threadIdx.x == 0) {
        int acc = 0;
#pragma unroll 8
        for (int b = 0; b < NBC; b++) { boff[b] = acc; acc += tot[b]; }
        boff[NBC] = acc;                           // == NE
    }
}

// ---------------------------------------------------------------------------
// K3: scatter edges into dst-bucket order (LDS cursors, zero global atomics).
//     One packed int per edge: src(16b) | dst&63 (6b) | type (4b).
// ---------------------------------------------------------------------------
__global__ void __launch_bounds__(1024) k_scatA(const int* __restrict__ es,
                                                const int* __restrict__ ed,
                                                const int* __restrict__ et,
                                                const int* __restrict__ cpbx,
                                                const int* __restrict__ boff,
                                                int* __restrict__ bpack) {
    __shared__ int cur[NBC];
    const int start = blockIdx.x * CHUNK, end = min(start + CHUNK, NE);
    for (int i = threadIdx.x; i < NBC; i += 1024)
        cur[i] = boff[i] + cpbx[blockIdx.x * NBC + i];
    __syncthreads();
    for (int e = start + threadIdx.x; e += 0, e < end; e += 1024) {
        int s = es[e], d = ed[e], t = et[e];
        int slot = atomicAdd(&cur[d >> 6], 1);
        bpack[slot] = s | ((d & 63) << 16) | (t << 22);
    }
}

// ---------------------------------------------------------------------------
// K4: fused message + attention + aggregation + self-loop.
// One block per 64-node dst bucket. Basis trick: msg = sum_b w_comp[t,b]*(x@B_b)
// -> MFMA weights are type-independent, so tiles need no type purity and edges
// need only coarse dst grouping. Messages accumulate in fp32 LDS (atomicAdd),
// then self-loop GEMM + ReLU writes out[:,1,:]. No amsg round-trip.
// ---------------------------------------------------------------------------
__global__ void __launch_bounds__(256) k_msgagg(
    const unsigned short* __restrict__ bfrag, const unsigned short* __restrict__ afrag,
    const float* __restrict__ aproj, const float* __restrict__ w_comp,
    const float* __restrict__ B_w, const float* __restrict__ B_b,
    const int* __restrict__ boff, const int* __restrict__ bpack,
    const unsigned short* __restrict__ init_bf, const float* __restrict__ S,
    float* __restrict__ out) {
    __shared__ float acc[BNODE * 33];              // +1 pad: bank = (fine+col)%32
    const int tid = threadIdx.x, lane = tid & 63, wave = tid >> 6;
    const int b = blockIdx.x;
    for (int i = tid; i < BNODE * 33; i += 256) acc[i] = 0.f;
    const int s0 = boff[b], s1 = boff[b + 1];
    const int m = lane & 15, quad = lane >> 4;
    // fragment loads (uniform over tiles, kept in registers)
    const short8* bfp = (const short8*)bfrag;
    short8 wb00 = bfp[(0 * 2 + 0) * 64 + lane];
    short8 wb01 = bfp[(0 * 2 + 1) * 64 + lane];
    short8 wb10 = bfp[(1 * 2 + 0) * 64 + lane];
    short8 wb11 = bfp[(1 * 2 + 1) * 64 + lane];
    short8 wb20 = bfp[(2 * 2 + 0) * 64 + lane];
    short8 wb21 = bfp[(2 * 2 + 1) * 64 + lane];
    short8 wb30 = bfp[(3 * 2 + 0) * 64 + lane];
    short8 wb31 = bfp[(3 * 2 + 1) * 64 + lane];
    const short8* afp = (const short8*)afrag;
    short8 a00 = afp[(0 * 2 + 0) * 64 + lane];
    short8 a01 = afp[(0 * 2 + 1) * 64 + lane];
    short8 a10 = afp[(1 * 2 + 0) * 64 + lane];
    short8 a11 = afp[(1 * 2 + 1) * 64 + lane];
    const float bw0 = B_w[m], bw1 = B_w[m + 16], bb = B_b[0];
    __syncthreads();
    const int ntile = (s1 - s0 + 15) >> 4;
    for (int ti = wave; ti < ntile; ti += 4) {
        const int e0 = s0 + ti * 16;
        const int ea = e0 + m;
        int pk = (ea < s1) ? bpack[ea] : 0;
        int src = pk & 0xffff;
        int dst = (b << 6) + ((pk >> 16) & 63);
        short8 xa = *(const short8*)(init_bf + (size_t)src * 32 + quad * 8);
        short8 ya = *(const short8*)(init_bf + (size_t)dst * 32 + quad * 8);
        floatx4 z4 = {0.f, 0.f, 0.f, 0.f};
        floatx4 hc0 = __builtin_amdgcn_mfma_f32_16x16x32_bf16(xa, a00, z4, 0, 0, 0);
        hc0 = __builtin_amdgcn_mfma_f32_16x16x32_bf16(ya, a10, hc0, 0, 0, 0);
        floatx4 hc1 = __builtin_amdgcn_mfma_f32_16x16x32_bf16(xa, a01, z4, 0, 0, 0);
        hc1 = __builtin_amdgcn_mfma_f32_16x16x32_bf16(ya, a11, hc1, 0, 0, 0);
        floatx4 zb00 = __builtin_amdgcn_mfma_f32_16x16x32_bf16(xa, wb00, z4, 0, 0, 0);
        floatx4 zb10 = __builtin_amdgcn_mfma_f32_16x16x32_bf16(xa, wb10, z4, 0, 0, 0);
        floatx4 zb20 = __builtin_amdgcn_mfma_f32_16x16x32_bf16(xa, wb20, z4, 0, 0, 0);
        floatx4 zb30 = __builtin_amdgcn_mfma_f32_16x16x32_bf16(xa, wb30, z4, 0, 0, 0);
        floatx4 zb01 = __builtin_amdgcn_mfma_f32_16x16x32_bf16(xa, wb01, z4, 0, 0, 0);
        floatx4 zb11 = __builtin_amdgcn_mfma_f32_16x16x32_bf16(xa, wb11, z4, 0, 0, 0);
        floatx4 zb21 = __builtin_amdgcn_mfma_f32_16x16x32_bf16(xa, wb21, z4, 0, 0, 0);
        floatx4 zb31 = __builtin_amdgcn_mfma_f32_16x16x32_bf16(xa, wb31, z4, 0, 0, 0);
        int pkr[4];
        float part[4];
#pragma unroll
        for (int r = 0; r < 4; r++) {
            pkr[r] = __shfl(pk, quad * 20 + r, 64);   // lane holding edge quad*4+r
            int t_r = (pkr[r] >> 22) & 15;
            part[r] = fmaxf(hc0[r] + aproj[t_r * 32 + m], 0.f) * bw0
                    + fmaxf(hc1[r] + aproj[t_r * 32 + 16 + m], 0.f) * bw1;
        }
#pragma unroll
        for (int s = 1; s < 16; s <<= 1) {
#pragma unroll
            for (int r = 0; r < 4; r++) part[r] += __shfl_xor(part[r], s, 64);
        }
#pragma unroll
        for (int r = 0; r < 4; r++) {
            if (e0 + quad * 4 + r < s1) {
                int t_r = (pkr[r] >> 22) & 15;
                int f_r = (pkr[r] >> 16) & 63;
                const float4 wc = *(const float4*)(w_comp + t_r * 4);
                float a = 1.f / (1.f + __expf(-(part[r] + bb)));
                float m0 = wc.x * zb00[r] + wc.y * zb10[r] + wc.z * zb20[r] + wc.w * zb30[r];
                float m1 = wc.x * zb01[r] + wc.y * zb11[r] + wc.z * zb21[r] + wc.w * zb31[r];
                atomicAdd(&acc[f_r * 33 + m], a * m0);
                atomicAdd(&acc[f_r * 33 + 16 + m], a * m1);
            }
        }
    }
    __syncthreads();
    // self-loop GEMM + ReLU + store out[:,1,:]
    const int vl = tid >> 2, c0 = (tid & 3) * 8;
    const int v = b * BNODE + vl;
    if (v >= NN) return;
    float x[32];
    const float4* xp = (const float4*)(out + (size_t)v * 64);
#pragma unroll
    for (int q = 0; q < 8; q++) {
        float4 f = xp[q];
        x[4 * q] = f.x; x[4 * q + 1] = f.y; x[4 * q + 2] = f.z; x[4 * q + 3] = f.w;
    }
    float av[8];
#pragma unroll
    for (int j = 0; j < 8; j++) av[j] = acc[vl * 33 + c0 + j];
#pragma unroll
    for (int d = 0; d < 32; d++) {
        float xd = x[d];
#pragma unroll
        for (int j = 0; j < 8; j++) av[j] += xd * S[d * 32 + c0 + j];
    }
    float4* op = (float4*)(out + (size_t)v * 64 + 32 + c0);
#pragma unroll
    for (int q = 0; q < 2; q++) {
        float4 f;
        f.x = fmaxf(av[4 * q], 0.f);
        f.y = fmaxf(av[4 * q + 1], 0.f);
        f.z = fmaxf(av[4 * q + 2], 0.f);
        f.w = fmaxf(av[4 * q + 3], 0.f);
        op[q] = f;
    }
}

extern "C" void kernel_launch(void* const* d_in, const int* in_sizes, int n_in,
                              void* d_out, int out_size, void* d_ws, size_t ws_size,
                              hipStream_t stream) {
    const float* feat      = (const float*)d_in[0];
    const float* embed     = (const float*)d_in[1];
    const float* transform = (const float*)d_in[2];
    const float* weight    = (const float*)d_in[3];
    const float* w_comp    = (const float*)d_in[4];
    const float* self_w    = (const float*)d_in[5];
    const float* A_w       = (const float*)d_in[6];
    const float* A_b       = (const float*)d_in[7];
    const float* B_w       = (const float*)d_in[8];
    const float* B_b       = (const float*)d_in[9];
    const float* attn_emb  = (const float*)d_in[10];
    const int*   idx       = (const int*)d_in[11];
    const int*   edge_src  = (const int*)d_in[12];
    const int*   edge_dst  = (const int*)d_in[13];
    const int*   edge_type = (const int*)d_in[14];
    float* out = (float*)d_out;

    // -------- workspace layout (~8.8 MB) --------
    char* ws = (char*)d_ws;
    unsigned short* init_bf = (unsigned short*)ws;                       // 3,200,000 B
    unsigned short* bfrag   = (unsigned short*)(ws + 3200000);           // 8,192 B
    unsigned short* afrag   = (unsigned short*)(ws + 3208192);           // 4,096 B
    float*          aproj   = (float*)(ws + 3212288);                    // 2,048 B
    int* ip      = (int*)(ws + 3214336);
    int* boff    = ip;            ip += NBC + 2;        // 783 used
    int* cpb     = ip;            ip += ABLK * NBC;     // 200,192
    int* cpbx    = ip;            ip += ABLK * NBC;     // 200,192
    int* bpack   = ip;            ip += NE;             // 800,000

    k_pre<<<516, 256, 0, stream>>>(feat, embed, transform, idx, weight,
                                   A_w, A_b, attn_emb, edge_dst,
                                   out, init_bf, bfrag, afrag, aproj, cpb);
    k_scanB<<<1, 256, 0, stream>>>(cpb, cpbx, boff);
    k_scatA<<<ABLK, 1024, 0, stream>>>(edge_src, edge_dst, edge_type, cpbx, boff, bpack);
    k_msgagg<<<NBC, 256, 0, stream>>>(bfrag, afrag, aproj, w_comp, B_w, B_b,
                                      boff, bpack, init_bf, self_w, out);
}

// Round 3
// 344.072 us; speedup vs baseline: 1.1073x; 1.1073x over previous
//
#include <hip/hip_runtime.h>
#include <math.h>

#define NN 50000
#define NE 800000
#define NR 16
#define BNODE 64                          // nodes per dst bucket
#define NBC 782                           // ceil(50000/64) buckets
#define ABLK 256                          // chunks in count/scatter passes
#define CHUNK ((NE + ABLK - 1) / ABLK)    // 3125

typedef __attribute__((ext_vector_type(8))) short short8;
typedef __attribute__((ext_vector_type(4))) float floatx4;

__device__ __forceinline__ unsigned short f2bf(float x) {
    unsigned int u = __float_as_uint(x);
    u += 0x7fffu + ((u >> 16) & 1u);
    return (unsigned short)(u >> 16);
}

// ---------------------------------------------------------------------------
// K1 (fused): blocks [0,64): basis MFMA fragments (bf16) + attn frags + aproj
//             blocks [64,260): init_fea = concat(feat, embed[idx]) @ T
//             blocks [260,516): per-chunk coarse dst histogram (dst>>6)
// ---------------------------------------------------------------------------
__global__ void __launch_bounds__(256) k_pre(
    const float* __restrict__ feat, const float* __restrict__ emb,
    const float* __restrict__ T, const int* __restrict__ idx,
    const float* __restrict__ weight, const float* __restrict__ A_w,
    const float* __restrict__ A_b, const float* __restrict__ attn_emb,
    const int* __restrict__ ed,
    float* __restrict__ out, unsigned short* __restrict__ init_bf,
    unsigned short* __restrict__ bfrag, unsigned short* __restrict__ afrag,
    float* __restrict__ aproj, int* __restrict__ cpb) {
    if (blockIdx.x >= 260) {                       // ---- histogram section
        __shared__ int lc[NBC];
        const int cb = blockIdx.x - 260;
        for (int i = threadIdx.x; i < NBC; i += 256) lc[i] = 0;
        __syncthreads();
        const int start = cb * CHUNK, end = min(start + CHUNK, NE);
        for (int e = start + threadIdx.x; e < end; e += 256)
            atomicAdd(&lc[ed[e] >> 6], 1);
        __syncthreads();
        for (int i = threadIdx.x; i < NBC; i += 256) cpb[cb * NBC + i] = lc[i];
        return;
    }
    if (blockIdx.x < 64) {                         // ---- fragment section
        int g = blockIdx.x * 256 + threadIdx.x;    // g < 16384
        if (g < 4 * 2 * 64 * 8) {                  // bfrag: 4096 (1024 per basis)
            int b2 = g >> 10, rest = g & 1023;
            int h = rest >> 9, l = (rest >> 3) & 63, j = rest & 7;
            int k = (l >> 4) * 8 + j, n = (l & 15) + 16 * h;
            bfrag[g] = f2bf(weight[b2 * 1024 + k * 32 + n]);
        }
        if (g < 2 * 2 * 64 * 8) {                  // afrag: 2048 (1024 per ks)
            int ks = g >> 10, rest = g & 1023;
            int nt = rest >> 9, l = (rest >> 3) & 63, j = rest & 7;
            int k = ks * 32 + (l >> 4) * 8 + j, n = (l & 15) + 16 * nt;
            afrag[g] = f2bf(A_w[k * 32 + n]);
        }
        if (g < 16 * 32) {                         // aproj: 512
            int t = g >> 5, j = g & 31;
            float acc = A_b[j];
#pragma unroll
            for (int k = 0; k < 32; k++) acc += attn_emb[t * 32 + k] * A_w[(64 + k) * 32 + j];
            aproj[g] = acc;
        }
        return;
    }
    int i = (blockIdx.x - 64) * 256 + threadIdx.x; // ---- init_fea section
    if (i >= NN) return;
    float v[32], acc[32];
#pragma unroll
    for (int o = 0; o < 32; o++) acc[o] = 0.f;
    const float4* fp = (const float4*)(feat + (size_t)i * 32);
#pragma unroll
    for (int q = 0; q < 8; q++) {
        float4 f = fp[q];
        v[4 * q] = f.x; v[4 * q + 1] = f.y; v[4 * q + 2] = f.z; v[4 * q + 3] = f.w;
    }
#pragma unroll
    for (int d = 0; d < 32; d++) {
        float xd = v[d];
#pragma unroll
        for (int o = 0; o < 32; o++) acc[o] += xd * T[d * 32 + o];
    }
    int row = idx[i];
    const float4* ep = (const float4*)(emb + (size_t)row * 32);
#pragma unroll
    for (int q = 0; q < 8; q++) {
        float4 f = ep[q];
        v[4 * q] = f.x; v[4 * q + 1] = f.y; v[4 * q + 2] = f.z; v[4 * q + 3] = f.w;
    }
#pragma unroll
    for (int d = 0; d < 32; d++) {
        float xd = v[d];
#pragma unroll
        for (int o = 0; o < 32; o++) acc[o] += xd * T[(32 + d) * 32 + o];
    }
    float4* op = (float4*)(out + (size_t)i * 64);
#pragma unroll
    for (int q = 0; q < 8; q++) {
        float4 f;
        f.x = acc[4 * q]; f.y = acc[4 * q + 1]; f.z = acc[4 * q + 2]; f.w = acc[4 * q + 3];
        op[q] = f;
    }
    unsigned int w[16];
#pragma unroll
    for (int q = 0; q < 16; q++)
        w[q] = (unsigned int)f2bf(acc[2 * q]) | ((unsigned int)f2bf(acc[2 * q + 1]) << 16);
    uint4* bp = (uint4*)(init_bf + (size_t)i * 32);
#pragma unroll
    for (int q = 0; q < 4; q++) {
        uint4 u; u.x = w[4 * q]; u.y = w[4 * q + 1]; u.z = w[4 * q + 2]; u.w = w[4 * q + 3];
        bp[q] = u;
    }
}

// ---------------------------------------------------------------------------
// K2a: per-bin scan over the 256 chunks (bins parallel across 4 blocks;
// loads coalesced across threads at each chunk step). Writes per-chunk
// relative cursors (cpbx) and per-bin totals (tot).
// ---------------------------------------------------------------------------
__global__ void __launch_bounds__(256) k_scan1(const int* __restrict__ cpb,
                                               int* __restrict__ cpbx,
                                               int* __restrict__ tot) {
    int bin = blockIdx.x * 256 + threadIdx.x;
    if (bin >= NBC) return;
    int run = 0;
#pragma unroll 8
    for (int c = 0; c < ABLK; c++) {
        int v = cpb[c * NBC + bin];
        cpbx[c * NBC + bin] = run;
        run += v;
    }
    tot[bin] = run;
}

// ---------------------------------------------------------------------------
// K2b: single-block Hillis-Steele prefix over the 782 bucket totals -> boff.
// ---------------------------------------------------------------------------
__global__ void __launch_bounds__(1024) k_scan2(const int* __restrict__ tot,
                                                int* __restrict__ boff) {
    __shared__ int ls[1024];
    int t = threadIdx.x;
    int v = (t < NBC) ? tot[t] : 0;
    ls[t] = v;
    __syncthreads();
    for (int off = 1; off < 1024; off <<= 1) {
        int u = (t >= off) ? ls[t - off] : 0;
        __syncthreads();
        ls[t] += u;
        __syncthreads();
    }
    if (t < NBC) boff[t] = ls[t] - v;          // exclusive
    if (t == NBC - 1) boff[NBC] = ls[t];       // == NE
}

// ---------------------------------------------------------------------------
// K3: scatter edges into dst-bucket order (LDS cursors, zero global atomics).
//     One packed int per edge: src(16b) | dst&63 (6b) | type (4b).
// ---------------------------------------------------------------------------
__global__ void __launch_bounds__(1024) k_scatA(const int* __restrict__ es,
                                                const int* __restrict__ ed,
                                                const int* __restrict__ et,
                                                const int* __restrict__ cpbx,
                                                const int* __restrict__ boff,
                                                int* __restrict__ bpack) {
    __shared__ int cur[NBC];
    const int start = blockIdx.x * CHUNK, end = min(start + CHUNK, NE);
    for (int i = threadIdx.x; i < NBC; i += 1024)
        cur[i] = boff[i] + cpbx[blockIdx.x * NBC + i];
    __syncthreads();
    for (int e = start + threadIdx.x; e < end; e += 1024) {
        int s = es[e], d = ed[e], t = et[e];
        int slot = atomicAdd(&cur[d >> 6], 1);
        bpack[slot] = s | ((d & 63) << 16) | (t << 22);
    }
}

// ---------------------------------------------------------------------------
// K4: fused message + attention + aggregation + self-loop.
// One block (8 waves) per 64-node dst bucket. Basis trick keeps MFMA weights
// type-independent. dst rows / aproj / w_comp staged in LDS; bpack prefetched
// one tile ahead; fp32 LDS accumulation; fused self-loop GEMM epilogue.
// ---------------------------------------------------------------------------
__global__ void __launch_bounds__(512) k_msgagg(
    const unsigned short* __restrict__ bfrag, const unsigned short* __restrict__ afrag,
    const float* __restrict__ aproj, const float* __restrict__ w_comp,
    const float* __restrict__ B_w, const float* __restrict__ B_b,
    const int* __restrict__ boff, const int* __restrict__ bpack,
    const unsigned short* __restrict__ init_bf, const float* __restrict__ S,
    float* __restrict__ out) {
    __shared__ float acc[BNODE * 33];              // +1 pad
    __shared__ unsigned short ystage[BNODE * 32];  // bucket's dst rows (bf16)
    __shared__ float aps[NR * 32];
    __shared__ float4 wcs[NR];
    const int tid = threadIdx.x, lane = tid & 63, wave = tid >> 6;
    const int b = blockIdx.x;
    const int nb0 = b * BNODE;
    for (int i = tid; i < BNODE * 33; i += 512) acc[i] = 0.f;
    for (int i = tid; i < BNODE * 4; i += 512) {   // stage 64 dst rows
        int node = nb0 + (i >> 2);
        short8 r = {0, 0, 0, 0, 0, 0, 0, 0};
        if (node < NN) r = *(const short8*)(init_bf + (size_t)node * 32 + (i & 3) * 8);
        ((short8*)ystage)[i] = r;
    }
    aps[tid < 512 ? tid : 0] = aproj[tid];         // 512 threads, 512 entries
    if (tid < NR) wcs[tid] = ((const float4*)w_comp)[tid];
    const int s0 = boff[b], s1 = boff[b + 1];
    const int m = lane & 15, quad = lane >> 4;
    const short8* bfp = (const short8*)bfrag;
    short8 wb00 = bfp[0 * 64 + lane];
    short8 wb01 = bfp[1 * 64 + lane];
    short8 wb10 = bfp[2 * 64 + lane];
    short8 wb11 = bfp[3 * 64 + lane];
    short8 wb20 = bfp[4 * 64 + lane];
    short8 wb21 = bfp[5 * 64 + lane];
    short8 wb30 = bfp[6 * 64 + lane];
    short8 wb31 = bfp[7 * 64 + lane];
    const short8* afp = (const short8*)afrag;
    short8 a00 = afp[0 * 64 + lane];
    short8 a01 = afp[1 * 64 + lane];
    short8 a10 = afp[2 * 64 + lane];
    short8 a11 = afp[3 * 64 + lane];
    const float bw0 = B_w[m], bw1 = B_w[m + 16], bb = B_b[0];
    __syncthreads();
    const int ntile = (s1 - s0 + 15) >> 4;
    int ti = wave;
    int pk = 0;
    if (ti < ntile) {
        int e = s0 + ti * 16 + m;
        pk = (e < s1) ? bpack[e] : 0;
    }
    for (; ti < ntile; ti += 8) {
        int pkn = 0;
        if (ti + 8 < ntile) {                      // prefetch next tile
            int e = s0 + (ti + 8) * 16 + m;
            pkn = (e < s1) ? bpack[e] : 0;
        }
        const int e0 = s0 + ti * 16;
        int src = pk & 0xffff;
        int f = (pk >> 16) & 63;
        short8 xa = *(const short8*)(init_bf + (size_t)src * 32 + quad * 8);
        short8 ya = ((const short8*)ystage)[f * 4 + quad];
        floatx4 z4 = {0.f, 0.f, 0.f, 0.f};
        floatx4 hc0 = __builtin_amdgcn_mfma_f32_16x16x32_bf16(xa, a00, z4, 0, 0, 0);
        hc0 = __builtin_amdgcn_mfma_f32_16x16x32_bf16(ya, a10, hc0, 0, 0, 0);
        floatx4 hc1 = __builtin_amdgcn_mfma_f32_16x16x32_bf16(xa, a01, z4, 0, 0, 0);
        hc1 = __builtin_amdgcn_mfma_f32_16x16x32_bf16(ya, a11, hc1, 0, 0, 0);
        floatx4 zb00 = __builtin_amdgcn_mfma_f32_16x16x32_bf16(xa, wb00, z4, 0, 0, 0);
        floatx4 zb10 = __builtin_amdgcn_mfma_f32_16x16x32_bf16(xa, wb10, z4, 0, 0, 0);
        floatx4 zb20 = __builtin_amdgcn_mfma_f32_16x16x32_bf16(xa, wb20, z4, 0, 0, 0);
        floatx4 zb30 = __builtin_amdgcn_mfma_f32_16x16x32_bf16(xa, wb30, z4, 0, 0, 0);
        floatx4 zb01 = __builtin_amdgcn_mfma_f32_16x16x32_bf16(xa, wb01, z4, 0, 0, 0);
        floatx4 zb11 = __builtin_amdgcn_mfma_f32_16x16x32_bf16(xa, wb11, z4, 0, 0, 0);
        floatx4 zb21 = __builtin_amdgcn_mfma_f32_16x16x32_bf16(xa, wb21, z4, 0, 0, 0);
        floatx4 zb31 = __builtin_amdgcn_mfma_f32_16x16x32_bf16(xa, wb31, z4, 0, 0, 0);
        int pkr[4];
        float part[4];
#pragma unroll
        for (int r = 0; r < 4; r++) {
            pkr[r] = __shfl(pk, quad * 20 + r, 64);   // lane 16*quad + (quad*4+r)
            int t_r = (pkr[r] >> 22) & 15;
            part[r] = fmaxf(hc0[r] + aps[t_r * 32 + m], 0.f) * bw0
                    + fmaxf(hc1[r] + aps[t_r * 32 + 16 + m], 0.f) * bw1;
        }
#pragma unroll
        for (int s = 1; s < 16; s <<= 1) {
#pragma unroll
            for (int r = 0; r < 4; r++) part[r] += __shfl_xor(part[r], s, 64);
        }
#pragma unroll
        for (int r = 0; r < 4; r++) {
            if (e0 + quad * 4 + r < s1) {
                int t_r = (pkr[r] >> 22) & 15;
                int f_r = (pkr[r] >> 16) & 63;
                float4 wc = wcs[t_r];
                float a = 1.f / (1.f + __expf(-(part[r] + bb)));
                float m0 = wc.x * zb00[r] + wc.y * zb10[r] + wc.z * zb20[r] + wc.w * zb30[r];
                float m1 = wc.x * zb01[r] + wc.y * zb11[r] + wc.z * zb21[r] + wc.w * zb31[r];
                atomicAdd(&acc[f_r * 33 + m], a * m0);
                atomicAdd(&acc[f_r * 33 + 16 + m], a * m1);
            }
        }
        pk = pkn;
    }
    __syncthreads();
    // self-loop GEMM + ReLU + store out[:,1,:] (first 256 threads: 4/node)
    if (tid >= 256) return;
    const int vl = tid >> 2, c0 = (tid & 3) * 8;
    const int v = nb0 + vl;
    if (v >= NN) return;
    float x[32];
    const float4* xp = (const float4*)(out + (size_t)v * 64);
#pragma unroll
    for (int q = 0; q < 8; q++) {
        float4 f = xp[q];
        x[4 * q] = f.x; x[4 * q + 1] = f.y; x[4 * q + 2] = f.z; x[4 * q + 3] = f.w;
    }
    float av[8];
#pragma unroll
    for (int j = 0; j < 8; j++) av[j] = acc[vl * 33 + c0 + j];
#pragma unroll
    for (int d = 0; d < 32; d++) {
        float xd = x[d];
#pragma unroll
        for (int j = 0; j < 8; j++) av[j] += xd * S[d * 32 + c0 + j];
    }
    float4* op = (float4*)(out + (size_t)v * 64 + 32 + c0);
#pragma unroll
    for (int q = 0; q < 2; q++) {
        float4 f;
        f.x = fmaxf(av[4 * q], 0.f);
        f.y = fmaxf(av[4 * q + 1], 0.f);
        f.z = fmaxf(av[4 * q + 2], 0.f);
        f.w = fmaxf(av[4 * q + 3], 0.f);
        op[q] = f;
    }
}

extern "C" void kernel_launch(void* const* d_in, const int* in_sizes, int n_in,
                              void* d_out, int out_size, void* d_ws, size_t ws_size,
                              hipStream_t stream) {
    const float* feat      = (const float*)d_in[0];
    const float* embed     = (const float*)d_in[1];
    const float* transform = (const float*)d_in[2];
    const float* weight    = (const float*)d_in[3];
    const float* w_comp    = (const float*)d_in[4];
    const float* self_w    = (const float*)d_in[5];
    const float* A_w       = (const float*)d_in[6];
    const float* A_b       = (const float*)d_in[7];
    const float* B_w       = (const float*)d_in[8];
    const float* B_b       = (const float*)d_in[9];
    const float* attn_emb  = (const float*)d_in[10];
    const int*   idx       = (const int*)d_in[11];
    const int*   edge_src  = (const int*)d_in[12];
    const int*   edge_dst  = (const int*)d_in[13];
    const int*   edge_type = (const int*)d_in[14];
    float* out = (float*)d_out;

    // -------- workspace layout (~8 MB) --------
    char* ws = (char*)d_ws;
    unsigned short* init_bf = (unsigned short*)ws;                       // 3,200,000 B
    unsigned short* bfrag   = (unsigned short*)(ws + 3200000);           // 8,192 B
    unsigned short* afrag   = (unsigned short*)(ws + 3208192);           // 4,096 B
    float*          aproj   = (float*)(ws + 3212288);                    // 2,048 B
    int* ip      = (int*)(ws + 3214336);
    int* boff    = ip;            ip += NBC + 2;        // 783 used
    int* tot     = ip;            ip += 1024;
    int* cpb     = ip;            ip += ABLK * NBC;     // 200,192
    int* cpbx    = ip;            ip += ABLK * NBC;     // 200,192
    int* bpack   = ip;            ip += NE;             // 800,000

    k_pre<<<516, 256, 0, stream>>>(feat, embed, transform, idx, weight,
                                   A_w, A_b, attn_emb, edge_dst,
                                   out, init_bf, bfrag, afrag, aproj, cpb);
    k_scan1<<<4, 256, 0, stream>>>(cpb, cpbx, tot);
    k_scan2<<<1, 1024, 0, stream>>>(tot, boff);
    k_scatA<<<ABLK, 1024, 0, stream>>>(edge_src, edge_dst, edge_type, cpbx, boff, bpack);
    k_msgagg<<<NBC, 512, 0, stream>>>(bfrag, afrag, aproj, w_comp, B_w, B_b,
                                      boff, bpack, init_bf, self_w, out);
}

// Round 4
// 335.085 us; speedup vs baseline: 1.1370x; 1.0268x over previous
//
#include <hip/hip_runtime.h>
#include <math.h>

#define NN 50000
#define NE 800000
#define NR 16
#define BNODE 64                          // nodes per dst bucket
#define NBC 782                           // ceil(50000/64) buckets
#define ABLK 256                          // chunks in count/scatter passes
#define CHUNK ((NE + ABLK - 1) / ABLK)    // 3125

typedef __attribute__((ext_vector_type(8))) short short8;
typedef __attribute__((ext_vector_type(4))) float floatx4;

__device__ __forceinline__ unsigned short f2bf(float x) {
    unsigned int u = __float_as_uint(x);
    u += 0x7fffu + ((u >> 16) & 1u);
    return (unsigned short)(u >> 16);
}

// ---------------------------------------------------------------------------
// K1 (fused): blocks [0,64): basis MFMA fragments (bf16) + attn frags + aproj
//             blocks [64,260): init_fea = concat(feat, embed[idx]) @ T
//             blocks [260,516): per-chunk coarse dst histogram (dst>>6)
// ---------------------------------------------------------------------------
__global__ void __launch_bounds__(256) k_pre(
    const float* __restrict__ feat, const float* __restrict__ emb,
    const float* __restrict__ T, const int* __restrict__ idx,
    const float* __restrict__ weight, const float* __restrict__ A_w,
    const float* __restrict__ A_b, const float* __restrict__ attn_emb,
    const int* __restrict__ ed,
    float* __restrict__ out, unsigned short* __restrict__ init_bf,
    unsigned short* __restrict__ bfrag, unsigned short* __restrict__ afrag,
    float* __restrict__ aproj, int* __restrict__ cpb) {
    if (blockIdx.x >= 260) {                       // ---- histogram section
        __shared__ int lc[NBC];
        const int cb = blockIdx.x - 260;
        for (int i = threadIdx.x; i < NBC; i += 256) lc[i] = 0;
        __syncthreads();
        const int start = cb * CHUNK, end = min(start + CHUNK, NE);
        for (int e = start + threadIdx.x; e < end; e += 256)
            atomicAdd(&lc[ed[e] >> 6], 1);
        __syncthreads();
        for (int i = threadIdx.x; i < NBC; i += 256) cpb[cb * NBC + i] = lc[i];
        return;
    }
    if (blockIdx.x < 64) {                         // ---- fragment section
        int g = blockIdx.x * 256 + threadIdx.x;    // g < 16384
        if (g < 4 * 2 * 64 * 8) {                  // bfrag: 4096 (1024 per basis)
            int b2 = g >> 10, rest = g & 1023;
            int h = rest >> 9, l = (rest >> 3) & 63, j = rest & 7;
            int k = (l >> 4) * 8 + j, n = (l & 15) + 16 * h;
            bfrag[g] = f2bf(weight[b2 * 1024 + k * 32 + n]);
        }
        if (g < 2 * 2 * 64 * 8) {                  // afrag: 2048 (1024 per ks)
            int ks = g >> 10, rest = g & 1023;
            int nt = rest >> 9, l = (rest >> 3) & 63, j = rest & 7;
            int k = ks * 32 + (l >> 4) * 8 + j, n = (l & 15) + 16 * nt;
            afrag[g] = f2bf(A_w[k * 32 + n]);
        }
        if (g < 16 * 32) {                         // aproj: 512
            int t = g >> 5, j = g & 31;
            float acc = A_b[j];
#pragma unroll
            for (int k = 0; k < 32; k++) acc += attn_emb[t * 32 + k] * A_w[(64 + k) * 32 + j];
            aproj[g] = acc;
        }
        return;
    }
    int i = (blockIdx.x - 64) * 256 + threadIdx.x; // ---- init_fea section
    if (i >= NN) return;
    float v[32], acc[32];
#pragma unroll
    for (int o = 0; o < 32; o++) acc[o] = 0.f;
    const float4* fp = (const float4*)(feat + (size_t)i * 32);
#pragma unroll
    for (int q = 0; q < 8; q++) {
        float4 f = fp[q];
        v[4 * q] = f.x; v[4 * q + 1] = f.y; v[4 * q + 2] = f.z; v[4 * q + 3] = f.w;
    }
#pragma unroll
    for (int d = 0; d < 32; d++) {
        float xd = v[d];
#pragma unroll
        for (int o = 0; o < 32; o++) acc[o] += xd * T[d * 32 + o];
    }
    int row = idx[i];
    const float4* ep = (const float4*)(emb + (size_t)row * 32);
#pragma unroll
    for (int q = 0; q < 8; q++) {
        float4 f = ep[q];
        v[4 * q] = f.x; v[4 * q + 1] = f.y; v[4 * q + 2] = f.z; v[4 * q + 3] = f.w;
    }
#pragma unroll
    for (int d = 0; d < 32; d++) {
        float xd = v[d];
#pragma unroll
        for (int o = 0; o < 32; o++) acc[o] += xd * T[(32 + d) * 32 + o];
    }
    float4* op = (float4*)(out + (size_t)i * 64);
#pragma unroll
    for (int q = 0; q < 8; q++) {
        float4 f;
        f.x = acc[4 * q]; f.y = acc[4 * q + 1]; f.z = acc[4 * q + 2]; f.w = acc[4 * q + 3];
        op[q] = f;
    }
    unsigned int w[16];
#pragma unroll
    for (int q = 0; q < 16; q++)
        w[q] = (unsigned int)f2bf(acc[2 * q]) | ((unsigned int)f2bf(acc[2 * q + 1]) << 16);
    uint4* bp = (uint4*)(init_bf + (size_t)i * 32);
#pragma unroll
    for (int q = 0; q < 4; q++) {
        uint4 u; u.x = w[4 * q]; u.y = w[4 * q + 1]; u.z = w[4 * q + 2]; u.w = w[4 * q + 3];
        bp[q] = u;
    }
}

// ---------------------------------------------------------------------------
// K2a: per-bin scan over the 256 chunks.
// ---------------------------------------------------------------------------
__global__ void __launch_bounds__(256) k_scan1(const int* __restrict__ cpb,
                                               int* __restrict__ cpbx,
                                               int* __restrict__ tot) {
    int bin = blockIdx.x * 256 + threadIdx.x;
    if (bin >= NBC) return;
    int run = 0;
#pragma unroll 8
    for (int c = 0; c < ABLK; c++) {
        int v = cpb[c * NBC + bin];
        cpbx[c * NBC + bin] = run;
        run += v;
    }
    tot[bin] = run;
}

// ---------------------------------------------------------------------------
// K2b: single-block Hillis-Steele prefix over the 782 bucket totals -> boff.
// ---------------------------------------------------------------------------
__global__ void __launch_bounds__(1024) k_scan2(const int* __restrict__ tot,
                                                int* __restrict__ boff) {
    __shared__ int ls[1024];
    int t = threadIdx.x;
    int v = (t < NBC) ? tot[t] : 0;
    ls[t] = v;
    __syncthreads();
    for (int off = 1; off < 1024; off <<= 1) {
        int u = (t >= off) ? ls[t - off] : 0;
        __syncthreads();
        ls[t] += u;
        __syncthreads();
    }
    if (t < NBC) boff[t] = ls[t] - v;          // exclusive
    if (t == NBC - 1) boff[NBC] = ls[t];       // == NE
}

// ---------------------------------------------------------------------------
// K3: scatter edges into dst-bucket order (LDS cursors, zero global atomics).
//     One packed int per edge: src(16b) | dst&63 (6b) | type (4b).
// ---------------------------------------------------------------------------
__global__ void __launch_bounds__(1024) k_scatA(const int* __restrict__ es,
                                                const int* __restrict__ ed,
                                                const int* __restrict__ et,
                                                const int* __restrict__ cpbx,
                                                const int* __restrict__ boff,
                                                int* __restrict__ bpack) {
    __shared__ int cur[NBC];
    const int start = blockIdx.x * CHUNK, end = min(start + CHUNK, NE);
    for (int i = threadIdx.x; i < NBC; i += 1024)
        cur[i] = boff[i] + cpbx[blockIdx.x * NBC + i];
    __syncthreads();
    for (int e = start + threadIdx.x; e < end; e += 1024) {
        int s = es[e], d = ed[e], t = et[e];
        int slot = atomicAdd(&cur[d >> 6], 1);
        bpack[slot] = s | ((d & 63) << 16) | (t << 22);
    }
}

// ---------------------------------------------------------------------------
// K4: fused message + attention + aggregation + self-loop.
// One block (8 waves) per 64-node dst bucket.
// SPILL FIX (R4): all 12 MFMA fragments live in LDS (ds_read just before use,
// ~1-instr live range instead of whole-loop); basis accumulators collapsed
// 32->16 VGPRs by folding w_comp per basis; 2-deep pk/xa pipeline.
// launch_bounds(512,4) caps at 128 VGPR -> no scratch.
// ---------------------------------------------------------------------------
__global__ void __launch_bounds__(512, 4) k_msgagg(
    const unsigned short* __restrict__ bfrag, const unsigned short* __restrict__ afrag,
    const float* __restrict__ aproj, const float* __restrict__ w_comp,
    const float* __restrict__ B_w, const float* __restrict__ B_b,
    const int* __restrict__ boff, const int* __restrict__ bpack,
    const unsigned short* __restrict__ init_bf, const float* __restrict__ S,
    float* __restrict__ out) {
    __shared__ float acc[BNODE * 33];              // 8448 B, +1 pad
    __shared__ unsigned short ystage[BNODE * 32];  // 4096 B: bucket's dst rows
    __shared__ unsigned short fr[12 * 512];        // 12288 B: 8 basis + 4 attn frags
    __shared__ float aps[NR * 32];                 // 2048 B
    __shared__ float4 wcs[NR];                     // 256 B
    const int tid = threadIdx.x, lane = tid & 63, wave = tid >> 6;
    const int b = blockIdx.x, nb0 = b * BNODE;
    for (int i = tid; i < BNODE * 33; i += 512) acc[i] = 0.f;
    for (int i = tid; i < BNODE * 4; i += 512) {   // stage 64 dst rows
        int node = nb0 + (i >> 2);
        short8 r = {0, 0, 0, 0, 0, 0, 0, 0};
        if (node < NN) r = *(const short8*)(init_bf + (size_t)node * 32 + (i & 3) * 8);
        ((short8*)ystage)[i] = r;
    }
    for (int i = tid; i < 768; i += 512) {         // stage frags: slots 0-7 basis, 8-11 attn
        short8 v = (i < 512) ? ((const short8*)bfrag)[i] : ((const short8*)afrag)[i - 512];
        ((short8*)fr)[i] = v;
    }
    aps[tid] = aproj[tid];                         // 512 threads, 512 entries
    if (tid < NR) wcs[tid] = ((const float4*)w_comp)[tid];
    const int s0 = boff[b], s1 = boff[b + 1];
    const int m = lane & 15, quad = lane >> 4;
    const float bw0 = B_w[m], bw1 = B_w[m + 16], bbias = B_b[0];
    __syncthreads();
    const short8* frp = (const short8*)fr;         // frp[g*64 + lane]
    const short8 z8 = {0, 0, 0, 0, 0, 0, 0, 0};
    const int ntile = (s1 - s0 + 15) >> 4;
    int ti = wave;
    int pk0 = 0, pk1 = 0;
    short8 xa0 = z8;
    if (ti < ntile) {
        int e = s0 + ti * 16 + m;
        pk0 = (e < s1) ? bpack[e] : 0;
    }
    if (ti + 8 < ntile) {
        int e = s0 + (ti + 8) * 16 + m;
        pk1 = (e < s1) ? bpack[e] : 0;
    }
    if (ti < ntile)
        xa0 = *(const short8*)(init_bf + (size_t)(pk0 & 0xffff) * 32 + quad * 8);
    for (; ti < ntile; ti += 8) {
        // ---- issue future loads first (hide latency under this tile's MFMAs)
        int pk2 = 0;
        if (ti + 16 < ntile) {
            int e2 = s0 + (ti + 16) * 16 + m;
            pk2 = (e2 < s1) ? bpack[e2] : 0;
        }
        short8 xa1 = z8;
        if (ti + 8 < ntile)
            xa1 = *(const short8*)(init_bf + (size_t)(pk1 & 0xffff) * 32 + quad * 8);
        // ---- per-edge metadata (available before MFMAs)
        int pkr[4];
        float4 wcr[4];
#pragma unroll
        for (int r = 0; r < 4; r++) {
            pkr[r] = __shfl(pk0, quad * 20 + r, 64);     // lane 16q + (4q+r)
            wcr[r] = wcs[(pkr[r] >> 22) & 15];
        }
        int f = (pk0 >> 16) & 63;
        short8 ya = ((const short8*)ystage)[f * 4 + quad];
        floatx4 z4 = {0.f, 0.f, 0.f, 0.f};
        // ---- attention MFMAs (frags from LDS, transient)
        floatx4 hc0 = __builtin_amdgcn_mfma_f32_16x16x32_bf16(xa0, frp[8 * 64 + lane], z4, 0, 0, 0);
        hc0 = __builtin_amdgcn_mfma_f32_16x16x32_bf16(ya, frp[10 * 64 + lane], hc0, 0, 0, 0);
        floatx4 hc1 = __builtin_amdgcn_mfma_f32_16x16x32_bf16(xa0, frp[9 * 64 + lane], z4, 0, 0, 0);
        hc1 = __builtin_amdgcn_mfma_f32_16x16x32_bf16(ya, frp[11 * 64 + lane], hc1, 0, 0, 0);
        // ---- basis message MFMAs, folded per basis (accs: 2x floatx4 only)
        floatx4 m0 = z4, m1 = z4;
#pragma unroll
        for (int bs = 0; bs < 4; bs++) {
            floatx4 zb0 = __builtin_amdgcn_mfma_f32_16x16x32_bf16(xa0, frp[(2 * bs) * 64 + lane], z4, 0, 0, 0);
            floatx4 zb1 = __builtin_amdgcn_mfma_f32_16x16x32_bf16(xa0, frp[(2 * bs + 1) * 64 + lane], z4, 0, 0, 0);
#pragma unroll
            for (int r = 0; r < 4; r++) {
                float w = (bs == 0) ? wcr[r].x : (bs == 1) ? wcr[r].y : (bs == 2) ? wcr[r].z : wcr[r].w;
                m0[r] += w * zb0[r];
                m1[r] += w * zb1[r];
            }
        }
        // ---- attention MLP + reduce
        float part[4];
#pragma unroll
        for (int r = 0; r < 4; r++) {
            int t_r = (pkr[r] >> 22) & 15;
            part[r] = fmaxf(hc0[r] + aps[t_r * 32 + m], 0.f) * bw0
                    + fmaxf(hc1[r] + aps[t_r * 32 + 16 + m], 0.f) * bw1;
        }
#pragma unroll
        for (int s = 1; s < 16; s <<= 1) {
#pragma unroll
            for (int r = 0; r < 4; r++) part[r] += __shfl_xor(part[r], s, 64);
        }
        const int e0 = s0 + ti * 16;
#pragma unroll
        for (int r = 0; r < 4; r++) {
            if (e0 + quad * 4 + r < s1) {
                int f_r = (pkr[r] >> 16) & 63;
                float a = 1.f / (1.f + __expf(-(part[r] + bbias)));
                atomicAdd(&acc[f_r * 33 + m], a * m0[r]);
                atomicAdd(&acc[f_r * 33 + 16 + m], a * m1[r]);
            }
        }
        pk0 = pk1; pk1 = pk2; xa0 = xa1;
    }
    __syncthreads();
    // self-loop GEMM + ReLU + store out[:,1,:] (first 256 threads: 4/node)
    if (tid >= 256) return;
    const int vl = tid >> 2, c0 = (tid & 3) * 8;
    const int v = nb0 + vl;
    if (v >= NN) return;
    float x[32];
    const float4* xp = (const float4*)(out + (size_t)v * 64);
#pragma unroll
    for (int q = 0; q < 8; q++) {
        float4 f = xp[q];
        x[4 * q] = f.x; x[4 * q + 1] = f.y; x[4 * q + 2] = f.z; x[4 * q + 3] = f.w;
    }
    float av[8];
#pragma unroll
    for (int j = 0; j < 8; j++) av[j] = acc[vl * 33 + c0 + j];
#pragma unroll
    for (int d = 0; d < 32; d++) {
        float xd = x[d];
#pragma unroll
        for (int j = 0; j < 8; j++) av[j] += xd * S[d * 32 + c0 + j];
    }
    float4* op = (float4*)(out + (size_t)v * 64 + 32 + c0);
#pragma unroll
    for (int q = 0; q < 2; q++) {
        float4 f;
        f.x = fmaxf(av[4 * q], 0.f);
        f.y = fmaxf(av[4 * q + 1], 0.f);
        f.z = fmaxf(av[4 * q + 2], 0.f);
        f.w = fmaxf(av[4 * q + 3], 0.f);
        op[q] = f;
    }
}

extern "C" void kernel_launch(void* const* d_in, const int* in_sizes, int n_in,
                              void* d_out, int out_size, void* d_ws, size_t ws_size,
                              hipStream_t stream) {
    const float* feat      = (const float*)d_in[0];
    const float* embed     = (const float*)d_in[1];
    const float* transform = (const float*)d_in[2];
    const float* weight    = (const float*)d_in[3];
    const float* w_comp    = (const float*)d_in[4];
    const float* self_w    = (const float*)d_in[5];
    const float* A_w       = (const float*)d_in[6];
    const float* A_b       = (const float*)d_in[7];
    const float* B_w       = (const float*)d_in[8];
    const float* B_b       = (const float*)d_in[9];
    const float* attn_emb  = (const float*)d_in[10];
    const int*   idx       = (const int*)d_in[11];
    const int*   edge_src  = (const int*)d_in[12];
    const int*   edge_dst  = (const int*)d_in[13];
    const int*   edge_type = (const int*)d_in[14];
    float* out = (float*)d_out;

    // -------- workspace layout (~8 MB) --------
    char* ws = (char*)d_ws;
    unsigned short* init_bf = (unsigned short*)ws;                       // 3,200,000 B
    unsigned short* bfrag   = (unsigned short*)(ws + 3200000);           // 8,192 B
    unsigned short* afrag   = (unsigned short*)(ws + 3208192);           // 4,096 B
    float*          aproj   = (float*)(ws + 3212288);                    // 2,048 B
    int* ip      = (int*)(ws + 3214336);
    int* boff    = ip;            ip += NBC + 2;        // 783 used
    int* tot     = ip;            ip += 1024;
    int* cpb     = ip;            ip += ABLK * NBC;     // 200,192
    int* cpbx    = ip;            ip += ABLK * NBC;     // 200,192
    int* bpack   = ip;            ip += NE;             // 800,000

    k_pre<<<516, 256, 0, stream>>>(feat, embed, transform, idx, weight,
                                   A_w, A_b, attn_emb, edge_dst,
                                   out, init_bf, bfrag, afrag, aproj, cpb);
    k_scan1<<<4, 256, 0, stream>>>(cpb, cpbx, tot);
    k_scan2<<<1, 1024, 0, stream>>>(tot, boff);
    k_scatA<<<ABLK, 1024, 0, stream>>>(edge_src, edge_dst, edge_type, cpbx, boff, bpack);
    k_msgagg<<<NBC, 512, 0, stream>>>(bfrag, afrag, aproj, w_comp, B_w, B_b,
                                      boff, bpack, init_bf, self_w, out);
}

// Round 6
// 214.220 us; speedup vs baseline: 1.7785x; 1.5642x over previous
//
#include <hip/hip_runtime.h>
#include <math.h>

#define NN 50000
#define NE 800000
#define NR 16
#define BNODE 64                          // nodes per dst bucket
#define NBC 782                           // ceil(50000/64) buckets
#define ABLK 256                          // chunks in count/scatter passes
#define CHUNK ((NE + ABLK - 1) / ABLK)    // 3125
#define NTILE (NE / 16)                   // 50000 exact, no tail

typedef __attribute__((ext_vector_type(8))) short short8;
typedef __attribute__((ext_vector_type(4))) float floatx4;

__device__ __forceinline__ unsigned short f2bf(float x) {
    unsigned int u = __float_as_uint(x);
    u += 0x7fffu + ((u >> 16) & 1u);
    return (unsigned short)(u >> 16);
}
__device__ __forceinline__ float bf2f(unsigned short s) {
    return __uint_as_float(((unsigned int)s) << 16);
}

// ---------------------------------------------------------------------------
// K1 (fused): blocks [0,64): basis MFMA fragments (bf16) + attn frags + aproj
//             blocks [64,260): init_fea = concat(feat, embed[idx]) @ T
//             blocks [260,516): per-chunk coarse dst histogram (dst>>6)
// ---------------------------------------------------------------------------
__global__ void __launch_bounds__(256) k_pre(
    const float* __restrict__ feat, const float* __restrict__ emb,
    const float* __restrict__ T, const int* __restrict__ idx,
    const float* __restrict__ weight, const float* __restrict__ A_w,
    const float* __restrict__ A_b, const float* __restrict__ attn_emb,
    const int* __restrict__ ed,
    float* __restrict__ out, unsigned short* __restrict__ init_bf,
    unsigned short* __restrict__ bfrag, unsigned short* __restrict__ afrag,
    float* __restrict__ aproj, int* __restrict__ cpb) {
    if (blockIdx.x >= 260) {                       // ---- histogram section
        __shared__ int lc[NBC];
        const int cb = blockIdx.x - 260;
        for (int i = threadIdx.x; i < NBC; i += 256) lc[i] = 0;
        __syncthreads();
        const int start = cb * CHUNK, end = min(start + CHUNK, NE);
        for (int e = start + threadIdx.x; e < end; e += 256)
            atomicAdd(&lc[ed[e] >> 6], 1);
        __syncthreads();
        for (int i = threadIdx.x; i < NBC; i += 256) cpb[cb * NBC + i] = lc[i];
        return;
    }
    if (blockIdx.x < 64) {                         // ---- fragment section
        int g = blockIdx.x * 256 + threadIdx.x;    // g < 16384
        if (g < 4 * 2 * 64 * 8) {                  // bfrag: 4096 (1024 per basis)
            int b2 = g >> 10, rest = g & 1023;
            int h = rest >> 9, l = (rest >> 3) & 63, j = rest & 7;
            int k = (l >> 4) * 8 + j, n = (l & 15) + 16 * h;
            bfrag[g] = f2bf(weight[b2 * 1024 + k * 32 + n]);
        }
        if (g < 2 * 2 * 64 * 8) {                  // afrag: 2048 (1024 per ks)
            int ks = g >> 10, rest = g & 1023;
            int nt = rest >> 9, l = (rest >> 3) & 63, j = rest & 7;
            int k = ks * 32 + (l >> 4) * 8 + j, n = (l & 15) + 16 * nt;
            afrag[g] = f2bf(A_w[k * 32 + n]);
        }
        if (g < 16 * 32) {                         // aproj: 512
            int t = g >> 5, j = g & 31;
            float acc = A_b[j];
#pragma unroll
            for (int k = 0; k < 32; k++) acc += attn_emb[t * 32 + k] * A_w[(64 + k) * 32 + j];
            aproj[g] = acc;
        }
        return;
    }
    int i = (blockIdx.x - 64) * 256 + threadIdx.x; // ---- init_fea section
    if (i >= NN) return;
    float v[32], acc[32];
#pragma unroll
    for (int o = 0; o < 32; o++) acc[o] = 0.f;
    const float4* fp = (const float4*)(feat + (size_t)i * 32);
#pragma unroll
    for (int q = 0; q < 8; q++) {
        float4 f = fp[q];
        v[4 * q] = f.x; v[4 * q + 1] = f.y; v[4 * q + 2] = f.z; v[4 * q + 3] = f.w;
    }
#pragma unroll
    for (int d = 0; d < 32; d++) {
        float xd = v[d];
#pragma unroll
        for (int o = 0; o < 32; o++) acc[o] += xd * T[d * 32 + o];
    }
    int row = idx[i];
    const float4* ep = (const float4*)(emb + (size_t)row * 32);
#pragma unroll
    for (int q = 0; q < 8; q++) {
        float4 f = ep[q];
        v[4 * q] = f.x; v[4 * q + 1] = f.y; v[4 * q + 2] = f.z; v[4 * q + 3] = f.w;
    }
#pragma unroll
    for (int d = 0; d < 32; d++) {
        float xd = v[d];
#pragma unroll
        for (int o = 0; o < 32; o++) acc[o] += xd * T[(32 + d) * 32 + o];
    }
    float4* op = (float4*)(out + (size_t)i * 64);
#pragma unroll
    for (int q = 0; q < 8; q++) {
        float4 f;
        f.x = acc[4 * q]; f.y = acc[4 * q + 1]; f.z = acc[4 * q + 2]; f.w = acc[4 * q + 3];
        op[q] = f;
    }
    unsigned int w[16];
#pragma unroll
    for (int q = 0; q < 16; q++)
        w[q] = (unsigned int)f2bf(acc[2 * q]) | ((unsigned int)f2bf(acc[2 * q + 1]) << 16);
    uint4* bp = (uint4*)(init_bf + (size_t)i * 32);
#pragma unroll
    for (int q = 0; q < 4; q++) {
        uint4 u; u.x = w[4 * q]; u.y = w[4 * q + 1]; u.z = w[4 * q + 2]; u.w = w[4 * q + 3];
        bp[q] = u;
    }
}

// ---------------------------------------------------------------------------
// K2a: per-bin scan over the 256 chunks.
// ---------------------------------------------------------------------------
__global__ void __launch_bounds__(256) k_scan1(const int* __restrict__ cpb,
                                               int* __restrict__ cpbx,
                                               int* __restrict__ tot) {
    int bin = blockIdx.x * 256 + threadIdx.x;
    if (bin >= NBC) return;
    int run = 0;
#pragma unroll 8
    for (int c = 0; c < ABLK; c++) {
        int v = cpb[c * NBC + bin];
        cpbx[c * NBC + bin] = run;
        run += v;
    }
    tot[bin] = run;
}

// ---------------------------------------------------------------------------
// K2b: single-block Hillis-Steele prefix over the 782 bucket totals -> boff.
// ---------------------------------------------------------------------------
__global__ void __launch_bounds__(1024) k_scan2(const int* __restrict__ tot,
                                                int* __restrict__ boff) {
    __shared__ int ls[1024];
    int t = threadIdx.x;
    int v = (t < NBC) ? tot[t] : 0;
    ls[t] = v;
    __syncthreads();
    for (int off = 1; off < 1024; off <<= 1) {
        int u = (t >= off) ? ls[t - off] : 0;
        __syncthreads();
        ls[t] += u;
        __syncthreads();
    }
    if (t < NBC) boff[t] = ls[t] - v;          // exclusive
    if (t == NBC - 1) boff[NBC] = ls[t];       // == NE
}

// ---------------------------------------------------------------------------
// K3: scatter edges into dst-bucket order (LDS cursors, zero global atomics).
//     One packed int per edge: src(16b) | dst&63 (6b) | type (4b).
// ---------------------------------------------------------------------------
__global__ void __launch_bounds__(1024) k_scatA(const int* __restrict__ es,
                                                const int* __restrict__ ed,
                                                const int* __restrict__ et,
                                                const int* __restrict__ cpbx,
                                                const int* __restrict__ boff,
                                                int* __restrict__ bpack) {
    __shared__ int cur[NBC];
    const int start = blockIdx.x * CHUNK, end = min(start + CHUNK, NE);
    for (int i = threadIdx.x; i < NBC; i += 1024)
        cur[i] = boff[i] + cpbx[blockIdx.x * NBC + i];
    __syncthreads();
    for (int e = start + threadIdx.x; e < end; e += 1024) {
        int s = es[e], d = ed[e], t = et[e];
        int slot = atomicAdd(&cur[d >> 6], 1);
        bpack[slot] = s | ((d & 63) << 16) | (t << 22);
    }
}

// ---------------------------------------------------------------------------
// K4: fine counting sort within each 64-node bucket (one block per bucket).
// Produces row_off (CSR by dst) and the fully dst-sorted edge arrays
// e1 = src | (type<<16), e2 = dst. LDS atomics only.
// ---------------------------------------------------------------------------
__global__ void __launch_bounds__(256) k_fine(const int* __restrict__ boff,
                                              const int* __restrict__ bpack,
                                              int* __restrict__ row_off,
                                              int* __restrict__ e1,
                                              unsigned short* __restrict__ e2) {
    __shared__ int h[BNODE], ls[BNODE], cur[BNODE];
    const int b = blockIdx.x, tid = threadIdx.x;
    const int s0 = boff[b], s1 = boff[b + 1];
    if (tid < BNODE) h[tid] = 0;
    __syncthreads();
    for (int s = s0 + tid; s < s1; s += 256)
        atomicAdd(&h[(bpack[s] >> 16) & 63], 1);
    __syncthreads();
    if (tid < BNODE) ls[tid] = h[tid];
    __syncthreads();
    for (int off = 1; off < BNODE; off <<= 1) {
        int u = (tid < BNODE && tid >= off) ? ls[tid - off] : 0;
        __syncthreads();
        if (tid < BNODE) ls[tid] += u;
        __syncthreads();
    }
    if (tid < BNODE) {
        int excl = ls[tid] - h[tid];
        int node = b * BNODE + tid;
        if (node <= NN) row_off[node] = s0 + excl;   // covers row_off[NN]=NE
        cur[tid] = s0 + excl;
    }
    __syncthreads();
    for (int s = s0 + tid; s < s1; s += 256) {
        int pk = bpack[s];
        int f = (pk >> 16) & 63;
        int p = atomicAdd(&cur[f], 1);
        e1[p] = (pk & 0xffff) | (((pk >> 22) & 15) << 16);
        e2[p] = (unsigned short)(b * BNODE + f);
    }
}

// ---------------------------------------------------------------------------
// K5: edge-tile MFMA kernel. One 16-edge dst-sorted tile per wave, no LDS,
// no type purity needed (basis trick: msg = sum_b w_comp[t,b]*(x@B_b)).
//   hid = x @ A_w0 + y @ A_w1 + aproj[t]
//   a = sigmoid(relu(hid) . B_w + B_b); amsg[tile] = bf16(a * msg) SEQUENTIAL.
// NE/16 = 50000 exact tiles -> no tail guards anywhere.
// ---------------------------------------------------------------------------
__global__ void __launch_bounds__(256) k_msg(
    const unsigned short* __restrict__ bfrag, const unsigned short* __restrict__ afrag,
    const float* __restrict__ aproj, const float* __restrict__ w_comp,
    const float* __restrict__ B_w, const float* __restrict__ B_b,
    const int* __restrict__ e1, const unsigned short* __restrict__ e2,
    const unsigned short* __restrict__ init_bf, unsigned short* __restrict__ amsg) {
    const int wave = threadIdx.x >> 6;
    const int lane = threadIdx.x & 63;
    const int ti = blockIdx.x * 4 + wave;          // < 50000 exact
    const int m = lane & 15, quad = lane >> 4;
    const int e = ti * 16 + m;
    const int ev = e1[e];
    const int src = ev & 0xffff;
    const int dst = e2[e];
    short8 xa = *(const short8*)(init_bf + (size_t)src * 32 + quad * 8);
    short8 ya = *(const short8*)(init_bf + (size_t)dst * 32 + quad * 8);
    const short8* bfp = (const short8*)bfrag;
    const short8* afp = (const short8*)afrag;
    floatx4 z4 = {0.f, 0.f, 0.f, 0.f};
    // attention MFMAs
    floatx4 hc0 = __builtin_amdgcn_mfma_f32_16x16x32_bf16(xa, afp[0 * 64 + lane], z4, 0, 0, 0);
    hc0 = __builtin_amdgcn_mfma_f32_16x16x32_bf16(ya, afp[2 * 64 + lane], hc0, 0, 0, 0);
    floatx4 hc1 = __builtin_amdgcn_mfma_f32_16x16x32_bf16(xa, afp[1 * 64 + lane], z4, 0, 0, 0);
    hc1 = __builtin_amdgcn_mfma_f32_16x16x32_bf16(ya, afp[3 * 64 + lane], hc1, 0, 0, 0);
    // per-edge metadata (edge quad*4+r lives on lane 16*quad + (quad*4+r))
    int tr[4];
    float4 wcr[4];
#pragma unroll
    for (int r = 0; r < 4; r++) {
        int evr = __shfl(ev, quad * 20 + r, 64);
        tr[r] = (evr >> 16) & 15;
        wcr[r] = ((const float4*)w_comp)[tr[r]];
    }
    // basis message MFMAs, folded per basis
    floatx4 m0 = z4, m1 = z4;
#pragma unroll
    for (int bs = 0; bs < 4; bs++) {
        floatx4 zb0 = __builtin_amdgcn_mfma_f32_16x16x32_bf16(xa, bfp[(2 * bs) * 64 + lane], z4, 0, 0, 0);
        floatx4 zb1 = __builtin_amdgcn_mfma_f32_16x16x32_bf16(xa, bfp[(2 * bs + 1) * 64 + lane], z4, 0, 0, 0);
#pragma unroll
        for (int r = 0; r < 4; r++) {
            float w = (bs == 0) ? wcr[r].x : (bs == 1) ? wcr[r].y : (bs == 2) ? wcr[r].z : wcr[r].w;
            m0[r] += w * zb0[r];
            m1[r] += w * zb1[r];
        }
    }
    // attention MLP + 16-col reduce within each quad
    const float bw0 = B_w[m], bw1 = B_w[m + 16], bb = B_b[0];
    float part[4];
#pragma unroll
    for (int r = 0; r < 4; r++)
        part[r] = fmaxf(hc0[r] + aproj[tr[r] * 32 + m], 0.f) * bw0
                + fmaxf(hc1[r] + aproj[tr[r] * 32 + 16 + m], 0.f) * bw1;
#pragma unroll
    for (int s = 1; s < 16; s <<= 1) {
#pragma unroll
        for (int r = 0; r < 4; r++) part[r] += __shfl_xor(part[r], s, 64);
    }
#pragma unroll
    for (int r = 0; r < 4; r++) {
        const int p = ti * 16 + quad * 4 + r;      // sequential: edges already dst-sorted
        float a = 1.f / (1.f + __expf(-(part[r] + bb)));
        amsg[(size_t)p * 32 + m] = f2bf(a * m0[r]);
        amsg[(size_t)p * 32 + m + 16] = f2bf(a * m1[r]);
    }
}

// ---------------------------------------------------------------------------
// K6: dst-major aggregation + fused self-loop GEMM + ReLU (streaming amsg).
// ---------------------------------------------------------------------------
__global__ void __launch_bounds__(256) k_agg(
    const int* __restrict__ row_off, const unsigned short* __restrict__ amsg,
    const float* __restrict__ S, float* __restrict__ out) {
    int tid = threadIdx.x;
    int v = blockIdx.x * 64 + (tid >> 2);
    if (v >= NN) return;
    int c0 = (tid & 3) * 8;
    float acc[8];
#pragma unroll
    for (int j = 0; j < 8; j++) acc[j] = 0.f;
    int p0 = row_off[v], p1 = row_off[v + 1];
    for (int p = p0; p < p1; p++) {
        short8 mv = *(const short8*)(amsg + (size_t)p * 32 + c0);
#pragma unroll
        for (int j = 0; j < 8; j++) acc[j] += bf2f((unsigned short)mv[j]);
    }
    float x[32];
    const float4* xp = (const float4*)(out + (size_t)v * 64);
#pragma unroll
    for (int q = 0; q < 8; q++) {
        float4 f = xp[q];
        x[4 * q] = f.x; x[4 * q + 1] = f.y; x[4 * q + 2] = f.z; x[4 * q + 3] = f.w;
    }
#pragma unroll
    for (int d = 0; d < 32; d++) {
        float xd = x[d];
#pragma unroll
        for (int j = 0; j < 8; j++) acc[j] += xd * S[d * 32 + c0 + j];
    }
    float4* op = (float4*)(out + (size_t)v * 64 + 32 + c0);
#pragma unroll
    for (int q = 0; q < 2; q++) {
        float4 f;
        f.x = fmaxf(acc[4 * q], 0.f);
        f.y = fmaxf(acc[4 * q + 1], 0.f);
        f.z = fmaxf(acc[4 * q + 2], 0.f);
        f.w = fmaxf(acc[4 * q + 3], 0.f);
        op[q] = f;
    }
}

extern "C" void kernel_launch(void* const* d_in, const int* in_sizes, int n_in,
                              void* d_out, int out_size, void* d_ws, size_t ws_size,
                              hipStream_t stream) {
    const float* feat      = (const float*)d_in[0];
    const float* embed     = (const float*)d_in[1];
    const float* transform = (const float*)d_in[2];
    const float* weight    = (const float*)d_in[3];
    const float* w_comp    = (const float*)d_in[4];
    const float* self_w    = (const float*)d_in[5];
    const float* A_w       = (const float*)d_in[6];
    const float* A_b       = (const float*)d_in[7];
    const float* B_w       = (const float*)d_in[8];
    const float* B_b       = (const float*)d_in[9];
    const float* attn_emb  = (const float*)d_in[10];
    const int*   idx       = (const int*)d_in[11];
    const int*   edge_src  = (const int*)d_in[12];
    const int*   edge_dst  = (const int*)d_in[13];
    const int*   edge_type = (const int*)d_in[14];
    float* out = (float*)d_out;

    // -------- workspace layout (~61 MB) --------
    char* ws = (char*)d_ws;
    unsigned short* amsg    = (unsigned short*)ws;                 // NE*64 B = 51,200,000
    int*            bpack   = (int*)ws;      // aliases amsg[0 .. NE*4B): consumed by k_fine
                                             // BEFORE k_msg overwrites the region.
    unsigned short* init_bf = (unsigned short*)(ws + (size_t)NE * 64);               // 3,200,000 B
    unsigned short* bfrag   = (unsigned short*)((char*)init_bf + 3200000);           // 8,192 B
    unsigned short* afrag   = (unsigned short*)((char*)bfrag + 8192);                // 4,096 B
    float*          aproj   = (float*)((char*)afrag + 4096);                         // 2,048 B
    int* ip      = (int*)((char*)aproj + 2048);
    int* boff    = ip;            ip += NBC + 2;        // 783 used
    int* tot     = ip;            ip += 1024;
    int* cpb     = ip;            ip += ABLK * NBC;     // 200,192
    int* cpbx    = ip;            ip += ABLK * NBC;     // 200,192
    int* row_off = ip;            ip += NN + 1;
    int* e1      = ip;            ip += NE;             // 3,200,000 B
    unsigned short* e2 = (unsigned short*)ip;           // 1,600,000 B

    k_pre<<<516, 256, 0, stream>>>(feat, embed, transform, idx, weight,
                                   A_w, A_b, attn_emb, edge_dst,
                                   out, init_bf, bfrag, afrag, aproj, cpb);
    k_scan1<<<4, 256, 0, stream>>>(cpb, cpbx, tot);
    k_scan2<<<1, 1024, 0, stream>>>(tot, boff);
    k_scatA<<<ABLK, 1024, 0, stream>>>(edge_src, edge_dst, edge_type, cpbx, boff, bpack);
    k_fine<<<NBC, 256, 0, stream>>>(boff, bpack, row_off, e1, e2);
    k_msg<<<NTILE / 4, 256, 0, stream>>>(bfrag, afrag, aproj, w_comp, B_w, B_b,
                                         e1, e2, init_bf, amsg);
    k_agg<<<(NN + 63) / 64, 256, 0, stream>>>(row_off, amsg, self_w, out);
}

// Round 7
// 209.338 us; speedup vs baseline: 1.8200x; 1.0233x over previous
//
#include <hip/hip_runtime.h>
#include <math.h>

#define NN 50000
#define NE 800000
#define NR 16
#define BNODE 64                          // nodes per dst bucket
#define NBC 782                           // ceil(50000/64) buckets
#define ABLK 256                          // chunks in count/scatter passes
#define CHUNK ((NE + ABLK - 1) / ABLK)    // 3125
#define NTILE (NE / 16)                   // 50000 exact, no tail
#define TPW 4                             // tiles per wave (50000/4/4 = 3125 blocks exact)

typedef __attribute__((ext_vector_type(8))) short short8;
typedef __attribute__((ext_vector_type(4))) float floatx4;

__device__ __forceinline__ unsigned short f2bf(float x) {
    unsigned int u = __float_as_uint(x);
    u += 0x7fffu + ((u >> 16) & 1u);
    return (unsigned short)(u >> 16);
}
__device__ __forceinline__ float bf2f(unsigned short s) {
    return __uint_as_float(((unsigned int)s) << 16);
}

// ---------------------------------------------------------------------------
// K1 (fused): blocks [0,64): basis MFMA fragments (bf16) + attn frags + aproj
//             blocks [64,260): init_fea = concat(feat, embed[idx]) @ T
//             blocks [260,516): per-chunk coarse dst histogram (dst>>6)
// ---------------------------------------------------------------------------
__global__ void __launch_bounds__(256) k_pre(
    const float* __restrict__ feat, const float* __restrict__ emb,
    const float* __restrict__ T, const int* __restrict__ idx,
    const float* __restrict__ weight, const float* __restrict__ A_w,
    const float* __restrict__ A_b, const float* __restrict__ attn_emb,
    const int* __restrict__ ed,
    float* __restrict__ out, unsigned short* __restrict__ init_bf,
    unsigned short* __restrict__ bfrag, unsigned short* __restrict__ afrag,
    float* __restrict__ aproj, int* __restrict__ cpb) {
    if (blockIdx.x >= 260) {                       // ---- histogram section
        __shared__ int lc[NBC];
        const int cb = blockIdx.x - 260;
        for (int i = threadIdx.x; i < NBC; i += 256) lc[i] = 0;
        __syncthreads();
        const int start = cb * CHUNK, end = min(start + CHUNK, NE);
        for (int e = start + threadIdx.x; e < end; e += 256)
            atomicAdd(&lc[ed[e] >> 6], 1);
        __syncthreads();
        for (int i = threadIdx.x; i < NBC; i += 256) cpb[cb * NBC + i] = lc[i];
        return;
    }
    if (blockIdx.x < 64) {                         // ---- fragment section
        int g = blockIdx.x * 256 + threadIdx.x;    // g < 16384
        if (g < 4 * 2 * 64 * 8) {                  // bfrag: 4096 (1024 per basis)
            int b2 = g >> 10, rest = g & 1023;
            int h = rest >> 9, l = (rest >> 3) & 63, j = rest & 7;
            int k = (l >> 4) * 8 + j, n = (l & 15) + 16 * h;
            bfrag[g] = f2bf(weight[b2 * 1024 + k * 32 + n]);
        }
        if (g < 2 * 2 * 64 * 8) {                  // afrag: 2048 (1024 per ks)
            int ks = g >> 10, rest = g & 1023;
            int nt = rest >> 9, l = (rest >> 3) & 63, j = rest & 7;
            int k = ks * 32 + (l >> 4) * 8 + j, n = (l & 15) + 16 * nt;
            afrag[g] = f2bf(A_w[k * 32 + n]);
        }
        if (g < 16 * 32) {                         // aproj: 512
            int t = g >> 5, j = g & 31;
            float acc = A_b[j];
#pragma unroll
            for (int k = 0; k < 32; k++) acc += attn_emb[t * 32 + k] * A_w[(64 + k) * 32 + j];
            aproj[g] = acc;
        }
        return;
    }
    int i = (blockIdx.x - 64) * 256 + threadIdx.x; // ---- init_fea section
    if (i >= NN) return;
    float v[32], acc[32];
#pragma unroll
    for (int o = 0; o < 32; o++) acc[o] = 0.f;
    const float4* fp = (const float4*)(feat + (size_t)i * 32);
#pragma unroll
    for (int q = 0; q < 8; q++) {
        float4 f = fp[q];
        v[4 * q] = f.x; v[4 * q + 1] = f.y; v[4 * q + 2] = f.z; v[4 * q + 3] = f.w;
    }
#pragma unroll
    for (int d = 0; d < 32; d++) {
        float xd = v[d];
#pragma unroll
        for (int o = 0; o < 32; o++) acc[o] += xd * T[d * 32 + o];
    }
    int row = idx[i];
    const float4* ep = (const float4*)(emb + (size_t)row * 32);
#pragma unroll
    for (int q = 0; q < 8; q++) {
        float4 f = ep[q];
        v[4 * q] = f.x; v[4 * q + 1] = f.y; v[4 * q + 2] = f.z; v[4 * q + 3] = f.w;
    }
#pragma unroll
    for (int d = 0; d < 32; d++) {
        float xd = v[d];
#pragma unroll
        for (int o = 0; o < 32; o++) acc[o] += xd * T[(32 + d) * 32 + o];
    }
    float4* op = (float4*)(out + (size_t)i * 64);
#pragma unroll
    for (int q = 0; q < 8; q++) {
        float4 f;
        f.x = acc[4 * q]; f.y = acc[4 * q + 1]; f.z = acc[4 * q + 2]; f.w = acc[4 * q + 3];
        op[q] = f;
    }
    unsigned int w[16];
#pragma unroll
    for (int q = 0; q < 16; q++)
        w[q] = (unsigned int)f2bf(acc[2 * q]) | ((unsigned int)f2bf(acc[2 * q + 1]) << 16);
    uint4* bp = (uint4*)(init_bf + (size_t)i * 32);
#pragma unroll
    for (int q = 0; q < 4; q++) {
        uint4 u; u.x = w[4 * q]; u.y = w[4 * q + 1]; u.z = w[4 * q + 2]; u.w = w[4 * q + 3];
        bp[q] = u;
    }
}

// ---------------------------------------------------------------------------
// K2a: per-bin scan over the 256 chunks.
// ---------------------------------------------------------------------------
__global__ void __launch_bounds__(256) k_scan1(const int* __restrict__ cpb,
                                               int* __restrict__ cpbx,
                                               int* __restrict__ tot) {
    int bin = blockIdx.x * 256 + threadIdx.x;
    if (bin >= NBC) return;
    int run = 0;
#pragma unroll 8
    for (int c = 0; c < ABLK; c++) {
        int v = cpb[c * NBC + bin];
        cpbx[c * NBC + bin] = run;
        run += v;
    }
    tot[bin] = run;
}

// ---------------------------------------------------------------------------
// K2b: single-block Hillis-Steele prefix over the 782 bucket totals -> boff.
// ---------------------------------------------------------------------------
__global__ void __launch_bounds__(1024) k_scan2(const int* __restrict__ tot,
                                                int* __restrict__ boff) {
    __shared__ int ls[1024];
    int t = threadIdx.x;
    int v = (t < NBC) ? tot[t] : 0;
    ls[t] = v;
    __syncthreads();
    for (int off = 1; off < 1024; off <<= 1) {
        int u = (t >= off) ? ls[t - off] : 0;
        __syncthreads();
        ls[t] += u;
        __syncthreads();
    }
    if (t < NBC) boff[t] = ls[t] - v;          // exclusive
    if (t == NBC - 1) boff[NBC] = ls[t];       // == NE
}

// ---------------------------------------------------------------------------
// K3: scatter edges into dst-bucket order (LDS cursors, zero global atomics).
//     One packed int per edge: src(16b) | dst&63 (6b) | type (4b).
// ---------------------------------------------------------------------------
__global__ void __launch_bounds__(1024) k_scatA(const int* __restrict__ es,
                                                const int* __restrict__ ed,
                                                const int* __restrict__ et,
                                                const int* __restrict__ cpbx,
                                                const int* __restrict__ boff,
                                                int* __restrict__ bpack) {
    __shared__ int cur[NBC];
    const int start = blockIdx.x * CHUNK, end = min(start + CHUNK, NE);
    for (int i = threadIdx.x; i < NBC; i += 1024)
        cur[i] = boff[i] + cpbx[blockIdx.x * NBC + i];
    __syncthreads();
    for (int e = start + threadIdx.x; e < end; e += 1024) {
        int s = es[e], d = ed[e], t = et[e];
        int slot = atomicAdd(&cur[d >> 6], 1);
        bpack[slot] = s | ((d & 63) << 16) | (t << 22);
    }
}

// ---------------------------------------------------------------------------
// K4: fine counting sort within each 64-node bucket (one block per bucket).
// Produces row_off (CSR by dst) and the fully dst-sorted edge arrays
// e1 = src | (type<<16), e2 = dst. LDS atomics only.
// ---------------------------------------------------------------------------
__global__ void __launch_bounds__(256) k_fine(const int* __restrict__ boff,
                                              const int* __restrict__ bpack,
                                              int* __restrict__ row_off,
                                              int* __restrict__ e1,
                                              unsigned short* __restrict__ e2) {
    __shared__ int h[BNODE], ls[BNODE], cur[BNODE];
    const int b = blockIdx.x, tid = threadIdx.x;
    const int s0 = boff[b], s1 = boff[b + 1];
    if (tid < BNODE) h[tid] = 0;
    __syncthreads();
    for (int s = s0 + tid; s < s1; s += 256)
        atomicAdd(&h[(bpack[s] >> 16) & 63], 1);
    __syncthreads();
    if (tid < BNODE) ls[tid] = h[tid];
    __syncthreads();
    for (int off = 1; off < BNODE; off <<= 1) {
        int u = (tid < BNODE && tid >= off) ? ls[tid - off] : 0;
        __syncthreads();
        if (tid < BNODE) ls[tid] += u;
        __syncthreads();
    }
    if (tid < BNODE) {
        int excl = ls[tid] - h[tid];
        int node = b * BNODE + tid;
        if (node <= NN) row_off[node] = s0 + excl;   // covers row_off[NN]=NE
        cur[tid] = s0 + excl;
    }
    __syncthreads();
    for (int s = s0 + tid; s < s1; s += 256) {
        int pk = bpack[s];
        int f = (pk >> 16) & 63;
        int p = atomicAdd(&cur[f], 1);
        e1[p] = (pk & 0xffff) | (((pk >> 22) & 15) << 16);
        e2[p] = (unsigned short)(b * BNODE + f);
    }
}

// ---------------------------------------------------------------------------
// K5: edge-tile MFMA kernel. TPW=4 dst-sorted 16-edge tiles per wave:
// fragments/constants hoisted once per wave, tile metadata loaded upfront,
// next tile's xa/ya gather issued before this tile's compute (1-deep pipe).
// amsg stored as packed u32 rows: u32[m] = bf16(col m) | bf16(col m+16)<<16.
// ---------------------------------------------------------------------------
__global__ void __launch_bounds__(256) k_msg(
    const unsigned short* __restrict__ bfrag, const unsigned short* __restrict__ afrag,
    const float* __restrict__ aproj, const float* __restrict__ w_comp,
    const float* __restrict__ B_w, const float* __restrict__ B_b,
    const int* __restrict__ e1, const unsigned short* __restrict__ e2,
    const unsigned short* __restrict__ init_bf, unsigned int* __restrict__ amsg32) {
    const int wave = threadIdx.x >> 6;
    const int lane = threadIdx.x & 63;
    const int m = lane & 15, quad = lane >> 4;
    const int t0 = (blockIdx.x * 4 + wave) * TPW;  // tile base, exact coverage
    // ---- hoisted fragments / constants (amortized over TPW tiles)
    const short8* bfp = (const short8*)bfrag;
    const short8* afp = (const short8*)afrag;
    short8 af0 = afp[0 * 64 + lane], af1 = afp[1 * 64 + lane];
    short8 af2 = afp[2 * 64 + lane], af3 = afp[3 * 64 + lane];
    short8 bf0 = bfp[0 * 64 + lane], bf1 = bfp[1 * 64 + lane];
    short8 bf2 = bfp[2 * 64 + lane], bf3 = bfp[3 * 64 + lane];
    short8 bf4 = bfp[4 * 64 + lane], bf5 = bfp[5 * 64 + lane];
    short8 bf6 = bfp[6 * 64 + lane], bf7 = bfp[7 * 64 + lane];
    const float bw0 = B_w[m], bw1 = B_w[m + 16], bb = B_b[0];
    const unsigned short* ibq = init_bf + quad * 8;
    // ---- all tile metadata upfront
    int ev[TPW]; int dv[TPW];
#pragma unroll
    for (int t = 0; t < TPW; t++) {
        ev[t] = e1[(t0 + t) * 16 + m];
        dv[t] = e2[(t0 + t) * 16 + m];
    }
    // ---- gather pipeline (1-deep)
    short8 xa = *(const short8*)(ibq + (size_t)(ev[0] & 0xffff) * 32);
    short8 ya = *(const short8*)(ibq + (size_t)dv[0] * 32);
    const short8 z8 = {0, 0, 0, 0, 0, 0, 0, 0};
#pragma unroll
    for (int t = 0; t < TPW; t++) {
        short8 xan = z8, yan = z8;
        if (t + 1 < TPW) {                         // prefetch next tile's rows
            xan = *(const short8*)(ibq + (size_t)(ev[t + 1] & 0xffff) * 32);
            yan = *(const short8*)(ibq + (size_t)dv[t + 1] * 32);
        }
        // per-edge metadata (edge quad*4+r lives on lane 16*quad + (quad*4+r))
        int tr[4];
        float4 wcr[4];
#pragma unroll
        for (int r = 0; r < 4; r++) {
            int evr = __shfl(ev[t], quad * 20 + r, 64);
            tr[r] = (evr >> 16) & 15;
            wcr[r] = ((const float4*)w_comp)[tr[r]];
        }
        floatx4 z4 = {0.f, 0.f, 0.f, 0.f};
        // attention MFMAs
        floatx4 hc0 = __builtin_amdgcn_mfma_f32_16x16x32_bf16(xa, af0, z4, 0, 0, 0);
        hc0 = __builtin_amdgcn_mfma_f32_16x16x32_bf16(ya, af2, hc0, 0, 0, 0);
        floatx4 hc1 = __builtin_amdgcn_mfma_f32_16x16x32_bf16(xa, af1, z4, 0, 0, 0);
        hc1 = __builtin_amdgcn_mfma_f32_16x16x32_bf16(ya, af3, hc1, 0, 0, 0);
        // basis message MFMAs, folded per basis
        floatx4 m0 = z4, m1 = z4;
        {
            floatx4 zb0 = __builtin_amdgcn_mfma_f32_16x16x32_bf16(xa, bf0, z4, 0, 0, 0);
            floatx4 zb1 = __builtin_amdgcn_mfma_f32_16x16x32_bf16(xa, bf1, z4, 0, 0, 0);
#pragma unroll
            for (int r = 0; r < 4; r++) { m0[r] += wcr[r].x * zb0[r]; m1[r] += wcr[r].x * zb1[r]; }
        }
        {
            floatx4 zb0 = __builtin_amdgcn_mfma_f32_16x16x32_bf16(xa, bf2, z4, 0, 0, 0);
            floatx4 zb1 = __builtin_amdgcn_mfma_f32_16x16x32_bf16(xa, bf3, z4, 0, 0, 0);
#pragma unroll
            for (int r = 0; r < 4; r++) { m0[r] += wcr[r].y * zb0[r]; m1[r] += wcr[r].y * zb1[r]; }
        }
        {
            floatx4 zb0 = __builtin_amdgcn_mfma_f32_16x16x32_bf16(xa, bf4, z4, 0, 0, 0);
            floatx4 zb1 = __builtin_amdgcn_mfma_f32_16x16x32_bf16(xa, bf5, z4, 0, 0, 0);
#pragma unroll
            for (int r = 0; r < 4; r++) { m0[r] += wcr[r].z * zb0[r]; m1[r] += wcr[r].z * zb1[r]; }
        }
        {
            floatx4 zb0 = __builtin_amdgcn_mfma_f32_16x16x32_bf16(xa, bf6, z4, 0, 0, 0);
            floatx4 zb1 = __builtin_amdgcn_mfma_f32_16x16x32_bf16(xa, bf7, z4, 0, 0, 0);
#pragma unroll
            for (int r = 0; r < 4; r++) { m0[r] += wcr[r].w * zb0[r]; m1[r] += wcr[r].w * zb1[r]; }
        }
        // attention MLP + 16-col reduce within each quad
        float part[4];
#pragma unroll
        for (int r = 0; r < 4; r++)
            part[r] = fmaxf(hc0[r] + aproj[tr[r] * 32 + m], 0.f) * bw0
                    + fmaxf(hc1[r] + aproj[tr[r] * 32 + 16 + m], 0.f) * bw1;
#pragma unroll
        for (int s = 1; s < 16; s <<= 1) {
#pragma unroll
            for (int r = 0; r < 4; r++) part[r] += __shfl_xor(part[r], s, 64);
        }
        const int ti = t0 + t;
#pragma unroll
        for (int r = 0; r < 4; r++) {
            const int p = ti * 16 + quad * 4 + r;  // sequential: edges dst-sorted
            float a = 1.f / (1.f + __expf(-(part[r] + bb)));
            unsigned int pk = (unsigned int)f2bf(a * m0[r])
                            | ((unsigned int)f2bf(a * m1[r]) << 16);
            amsg32[(size_t)p * 16 + m] = pk;
        }
        xa = xan; ya = yan;
    }
}

// ---------------------------------------------------------------------------
// K6: dst-major aggregation + fused self-loop GEMM + ReLU (streaming amsg).
// amsg rows are packed u32: u32[m] = bf16(col m) | bf16(col m+16)<<16.
// Thread covering cols c0..c0+7 reads u32[(c0&8)..(c0&8)+7], lo/hi half.
// ---------------------------------------------------------------------------
__global__ void __launch_bounds__(256) k_agg(
    const int* __restrict__ row_off, const unsigned int* __restrict__ amsg32,
    const float* __restrict__ S, float* __restrict__ out) {
    int tid = threadIdx.x;
    int v = blockIdx.x * 64 + (tid >> 2);
    if (v >= NN) return;
    int c0 = (tid & 3) * 8;
    const int base = c0 & 8;
    const bool hi = c0 >= 16;
    float acc[8];
#pragma unroll
    for (int j = 0; j < 8; j++) acc[j] = 0.f;
    int p0 = row_off[v], p1 = row_off[v + 1];
    for (int p = p0; p < p1; p++) {
        const uint4* rp = (const uint4*)(amsg32 + (size_t)p * 16 + base);
        uint4 u0 = rp[0], u1 = rp[1];
        unsigned int uu[8] = {u0.x, u0.y, u0.z, u0.w, u1.x, u1.y, u1.z, u1.w};
#pragma unroll
        for (int j = 0; j < 8; j++) {
            unsigned int raw = hi ? (uu[j] & 0xffff0000u) : (uu[j] << 16);
            acc[j] += __uint_as_float(raw);
        }
    }
    float x[32];
    const float4* xp = (const float4*)(out + (size_t)v * 64);
#pragma unroll
    for (int q = 0; q < 8; q++) {
        float4 f = xp[q];
        x[4 * q] = f.x; x[4 * q + 1] = f.y; x[4 * q + 2] = f.z; x[4 * q + 3] = f.w;
    }
#pragma unroll
    for (int d = 0; d < 32; d++) {
        float xd = x[d];
#pragma unroll
        for (int j = 0; j < 8; j++) acc[j] += xd * S[d * 32 + c0 + j];
    }
    float4* op = (float4*)(out + (size_t)v * 64 + 32 + c0);
#pragma unroll
    for (int q = 0; q < 2; q++) {
        float4 f;
        f.x = fmaxf(acc[4 * q], 0.f);
        f.y = fmaxf(acc[4 * q + 1], 0.f);
        f.z = fmaxf(acc[4 * q + 2], 0.f);
        f.w = fmaxf(acc[4 * q + 3], 0.f);
        op[q] = f;
    }
}

extern "C" void kernel_launch(void* const* d_in, const int* in_sizes, int n_in,
                              void* d_out, int out_size, void* d_ws, size_t ws_size,
                              hipStream_t stream) {
    const float* feat      = (const float*)d_in[0];
    const float* embed     = (const float*)d_in[1];
    const float* transform = (const float*)d_in[2];
    const float* weight    = (const float*)d_in[3];
    const float* w_comp    = (const float*)d_in[4];
    const float* self_w    = (const float*)d_in[5];
    const float* A_w       = (const float*)d_in[6];
    const float* A_b       = (const float*)d_in[7];
    const float* B_w       = (const float*)d_in[8];
    const float* B_b       = (const float*)d_in[9];
    const float* attn_emb  = (const float*)d_in[10];
    const int*   idx       = (const int*)d_in[11];
    const int*   edge_src  = (const int*)d_in[12];
    const int*   edge_dst  = (const int*)d_in[13];
    const int*   edge_type = (const int*)d_in[14];
    float* out = (float*)d_out;

    // -------- workspace layout (~61 MB) --------
    char* ws = (char*)d_ws;
    unsigned int*   amsg32  = (unsigned int*)ws;                   // NE*64 B = 51,200,000
    int*            bpack   = (int*)ws;      // aliases amsg32[0 .. NE*4B): consumed by k_fine
                                             // BEFORE k_msg overwrites the region.
    unsigned short* init_bf = (unsigned short*)(ws + (size_t)NE * 64);               // 3,200,000 B
    unsigned short* bfrag   = (unsigned short*)((char*)init_bf + 3200000);           // 8,192 B
    unsigned short* afrag   = (unsigned short*)((char*)bfrag + 8192);                // 4,096 B
    float*          aproj   = (float*)((char*)afrag + 4096);                         // 2,048 B
    int* ip      = (int*)((char*)aproj + 2048);
    int* boff    = ip;            ip += NBC + 2;        // 783 used
    int* tot     = ip;            ip += 1024;
    int* cpb     = ip;            ip += ABLK * NBC;     // 200,192
    int* cpbx    = ip;            ip += ABLK * NBC;     // 200,192
    int* row_off = ip;            ip += NN + 1;
    int* e1      = ip;            ip += NE;             // 3,200,000 B
    unsigned short* e2 = (unsigned short*)ip;           // 1,600,000 B

    k_pre<<<516, 256, 0, stream>>>(feat, embed, transform, idx, weight,
                                   A_w, A_b, attn_emb, edge_dst,
                                   out, init_bf, bfrag, afrag, aproj, cpb);
    k_scan1<<<4, 256, 0, stream>>>(cpb, cpbx, tot);
    k_scan2<<<1, 1024, 0, stream>>>(tot, boff);
    k_scatA<<<ABLK, 1024, 0, stream>>>(edge_src, edge_dst, edge_type, cpbx, boff, bpack);
    k_fine<<<NBC, 256, 0, stream>>>(boff, bpack, row_off, e1, e2);
    k_msg<<<NTILE / (4 * TPW), 256, 0, stream>>>(bfrag, afrag, aproj, w_comp, B_w, B_b,
                                                 e1, e2, init_bf, amsg32);
    k_agg<<<(NN + 63) / 64, 256, 0, stream>>>(row_off, amsg32, self_w, out);
}

// Round 9
// 196.361 us; speedup vs baseline: 1.9402x; 1.0661x over previous
//
#include <hip/hip_runtime.h>
#include <math.h>

#define NN 50000
#define NE 800000
#define NR 16
#define BNODE 64                          // nodes per dst bucket
#define NBC 782                           // ceil(50000/64) buckets
#define ABLK 256                          // chunks in count/scatter passes
#define CHUNK ((NE + ABLK - 1) / ABLK)    // 3125
#define NTILE (NE / 16)                   // 50000 exact, no tail
#define TPW 4                             // tiles per wave (50000/4/4 = 3125 blocks exact)

typedef __attribute__((ext_vector_type(8))) short short8;
typedef __attribute__((ext_vector_type(4))) float floatx4;

__device__ __forceinline__ unsigned short f2bf(float x) {
    unsigned int u = __float_as_uint(x);
    u += 0x7fffu + ((u >> 16) & 1u);
    return (unsigned short)(u >> 16);
}
__device__ __forceinline__ float bf2f(unsigned short s) {
    return __uint_as_float(((unsigned int)s) << 16);
}

// 16-lane (DPP-row) sum: every lane of each 16-lane row ends with the row total.
// row_ror:N = 0x120|N. Replaces 4x shfl_xor (ds_bpermute) with pure VALU.
__device__ __forceinline__ float rsum16(float x) {
    int t;
    t = __builtin_amdgcn_update_dpp(0, __float_as_int(x), 0x128, 0xF, 0xF, true);
    x += __int_as_float(t);
    t = __builtin_amdgcn_update_dpp(0, __float_as_int(x), 0x124, 0xF, 0xF, true);
    x += __int_as_float(t);
    t = __builtin_amdgcn_update_dpp(0, __float_as_int(x), 0x122, 0xF, 0xF, true);
    x += __int_as_float(t);
    t = __builtin_amdgcn_update_dpp(0, __float_as_int(x), 0x121, 0xF, 0xF, true);
    x += __int_as_float(t);
    return x;
}

// ---------------------------------------------------------------------------
// K1 (fused): blocks [0,64): basis MFMA fragments (bf16) + attn frags + aproj
//             blocks [64,260): init_fea = concat(feat, embed[idx]) @ T
//             blocks [260,516): per-chunk coarse dst histogram (dst>>6)
// ---------------------------------------------------------------------------
__global__ void __launch_bounds__(256) k_pre(
    const float* __restrict__ feat, const float* __restrict__ emb,
    const float* __restrict__ T, const int* __restrict__ idx,
    const float* __restrict__ weight, const float* __restrict__ A_w,
    const float* __restrict__ A_b, const float* __restrict__ attn_emb,
    const int* __restrict__ ed,
    float* __restrict__ out, unsigned short* __restrict__ init_bf,
    unsigned short* __restrict__ bfrag, unsigned short* __restrict__ afrag,
    float* __restrict__ aproj, int* __restrict__ cpb) {
    if (blockIdx.x >= 260) {                       // ---- histogram section
        __shared__ int lc[NBC];
        const int cb = blockIdx.x - 260;
        for (int i = threadIdx.x; i < NBC; i += 256) lc[i] = 0;
        __syncthreads();
        const int start = cb * CHUNK, end = min(start + CHUNK, NE);
        for (int e = start + threadIdx.x; e < end; e += 256)
            atomicAdd(&lc[ed[e] >> 6], 1);
        __syncthreads();
        for (int i = threadIdx.x; i < NBC; i += 256) cpb[cb * NBC + i] = lc[i];
        return;
    }
    if (blockIdx.x < 64) {                         // ---- fragment section
        int g = blockIdx.x * 256 + threadIdx.x;    // g < 16384
        if (g < 4 * 2 * 64 * 8) {                  // bfrag: 4096 (1024 per basis)
            int b2 = g >> 10, rest = g & 1023;
            int h = rest >> 9, l = (rest >> 3) & 63, j = rest & 7;
            int k = (l >> 4) * 8 + j, n = (l & 15) + 16 * h;
            bfrag[g] = f2bf(weight[b2 * 1024 + k * 32 + n]);
        }
        if (g < 2 * 2 * 64 * 8) {                  // afrag: 2048 (1024 per ks)
            int ks = g >> 10, rest = g & 1023;
            int nt = rest >> 9, l = (rest >> 3) & 63, j = rest & 7;
            int k = ks * 32 + (l >> 4) * 8 + j, n = (l & 15) + 16 * nt;
            afrag[g] = f2bf(A_w[k * 32 + n]);
        }
        if (g < 16 * 32) {                         // aproj: 512
            int t = g >> 5, j = g & 31;
            float acc = A_b[j];
#pragma unroll
            for (int k = 0; k < 32; k++) acc += attn_emb[t * 32 + k] * A_w[(64 + k) * 32 + j];
            aproj[g] = acc;
        }
        return;
    }
    int i = (blockIdx.x - 64) * 256 + threadIdx.x; // ---- init_fea section
    if (i >= NN) return;
    float v[32], acc[32];
#pragma unroll
    for (int o = 0; o < 32; o++) acc[o] = 0.f;
    const float4* fp = (const float4*)(feat + (size_t)i * 32);
#pragma unroll
    for (int q = 0; q < 8; q++) {
        float4 f = fp[q];
        v[4 * q] = f.x; v[4 * q + 1] = f.y; v[4 * q + 2] = f.z; v[4 * q + 3] = f.w;
    }
#pragma unroll
    for (int d = 0; d < 32; d++) {
        float xd = v[d];
#pragma unroll
        for (int o = 0; o < 32; o++) acc[o] += xd * T[d * 32 + o];
    }
    int row = idx[i];
    const float4* ep = (const float4*)(emb + (size_t)row * 32);
#pragma unroll
    for (int q = 0; q < 8; q++) {
        float4 f = ep[q];
        v[4 * q] = f.x; v[4 * q + 1] = f.y; v[4 * q + 2] = f.z; v[4 * q + 3] = f.w;
    }
#pragma unroll
    for (int d = 0; d < 32; d++) {
        float xd = v[d];
#pragma unroll
        for (int o = 0; o < 32; o++) acc[o] += xd * T[(32 + d) * 32 + o];
    }
    float4* op = (float4*)(out + (size_t)i * 64);
#pragma unroll
    for (int q = 0; q < 8; q++) {
        float4 f;
        f.x = acc[4 * q]; f.y = acc[4 * q + 1]; f.z = acc[4 * q + 2]; f.w = acc[4 * q + 3];
        op[q] = f;
    }
    unsigned int w[16];
#pragma unroll
    for (int q = 0; q < 16; q++)
        w[q] = (unsigned int)f2bf(acc[2 * q]) | ((unsigned int)f2bf(acc[2 * q + 1]) << 16);
    uint4* bp = (uint4*)(init_bf + (size_t)i * 32);
#pragma unroll
    for (int q = 0; q < 4; q++) {
        uint4 u; u.x = w[4 * q]; u.y = w[4 * q + 1]; u.z = w[4 * q + 2]; u.w = w[4 * q + 3];
        bp[q] = u;
    }
}

// ---------------------------------------------------------------------------
// K2a: per-bin scan over the 256 chunks.
// ---------------------------------------------------------------------------
__global__ void __launch_bounds__(256) k_scan1(const int* __restrict__ cpb,
                                               int* __restrict__ cpbx,
                                               int* __restrict__ tot) {
    int bin = blockIdx.x * 256 + threadIdx.x;
    if (bin >= NBC) return;
    int run = 0;
#pragma unroll 8
    for (int c = 0; c < ABLK; c++) {
        int v = cpb[c * NBC + bin];
        cpbx[c * NBC + bin] = run;
        run += v;
    }
    tot[bin] = run;
}

// ---------------------------------------------------------------------------
// K2b: single-block Hillis-Steele prefix over the 782 bucket totals -> boff.
// ---------------------------------------------------------------------------
__global__ void __launch_bounds__(1024) k_scan2(const int* __restrict__ tot,
                                                int* __restrict__ boff) {
    __shared__ int ls[1024];
    int t = threadIdx.x;
    int v = (t < NBC) ? tot[t] : 0;
    ls[t] = v;
    __syncthreads();
    for (int off = 1; off < 1024; off <<= 1) {
        int u = (t >= off) ? ls[t - off] : 0;
        __syncthreads();
        ls[t] += u;
        __syncthreads();
    }
    if (t < NBC) boff[t] = ls[t] - v;          // exclusive
    if (t == NBC - 1) boff[NBC] = ls[t];       // == NE
}

// ---------------------------------------------------------------------------
// K3: scatter edges into dst-bucket order (LDS cursors, zero global atomics).
//     One packed int per edge: src(16b) | dst&63 (6b) | type (4b).
// ---------------------------------------------------------------------------
__global__ void __launch_bounds__(1024) k_scatA(const int* __restrict__ es,
                                                const int* __restrict__ ed,
                                                const int* __restrict__ et,
                                                const int* __restrict__ cpbx,
                                                const int* __restrict__ boff,
                                                int* __restrict__ bpack) {
    __shared__ int cur[NBC];
    const int start = blockIdx.x * CHUNK, end = min(start + CHUNK, NE);
    for (int i = threadIdx.x; i < NBC; i += 1024)
        cur[i] = boff[i] + cpbx[blockIdx.x * NBC + i];
    __syncthreads();
    for (int e = start + threadIdx.x; e < end; e += 1024) {
        int s = es[e], d = ed[e], t = et[e];
        int slot = atomicAdd(&cur[d >> 6], 1);
        bpack[slot] = s | ((d & 63) << 16) | (t << 22);
    }
}

// ---------------------------------------------------------------------------
// K4: fine counting sort within each 64-node bucket (one block per bucket).
// Produces row_off (CSR by dst) and the fully dst-sorted edge arrays
// e1 = src | (type<<16), e2 = dst. LDS atomics only.
// ---------------------------------------------------------------------------
__global__ void __launch_bounds__(256) k_fine(const int* __restrict__ boff,
                                              const int* __restrict__ bpack,
                                              int* __restrict__ row_off,
                                              int* __restrict__ e1,
                                              unsigned short* __restrict__ e2) {
    __shared__ int h[BNODE], ls[BNODE], cur[BNODE];
    const int b = blockIdx.x, tid = threadIdx.x;
    const int s0 = boff[b], s1 = boff[b + 1];
    if (tid < BNODE) h[tid] = 0;
    __syncthreads();
    for (int s = s0 + tid; s < s1; s += 256)
        atomicAdd(&h[(bpack[s] >> 16) & 63], 1);
    __syncthreads();
    if (tid < BNODE) ls[tid] = h[tid];
    __syncthreads();
    for (int off = 1; off < BNODE; off <<= 1) {
        int u = (tid < BNODE && tid >= off) ? ls[tid - off] : 0;
        __syncthreads();
        if (tid < BNODE) ls[tid] += u;
        __syncthreads();
    }
    if (tid < BNODE) {
        int excl = ls[tid] - h[tid];
        int node = b * BNODE + tid;
        if (node <= NN) row_off[node] = s0 + excl;   // covers row_off[NN]=NE
        cur[tid] = s0 + excl;
    }
    __syncthreads();
    for (int s = s0 + tid; s < s1; s += 256) {
        int pk = bpack[s];
        int f = (pk >> 16) & 63;
        int p = atomicAdd(&cur[f], 1);
        e1[p] = (pk & 0xffff) | (((pk >> 22) & 15) << 16);
        e2[p] = (unsigned short)(b * BNODE + f);
    }
}

// ---------------------------------------------------------------------------
// K5: edge-tile MFMA kernel. TPW=4 dst-sorted 16-edge tiles per wave.
// R9 = R8 with the s_ap staging bug fixed (512 entries, 256 threads -> must
// stride-loop; R8's single-guard staging left types 8-15 as garbage LDS).
//  - per-edge metadata via one int4 load (quad-uniform) instead of 4 bpermutes
//  - 16-lane reduce via DPP row_ror adds instead of 16 ds_bpermutes
//  - aproj / w_comp staged in LDS (kills 12 scattered VMEM loads per tile)
//  - v_cvt_pk_bf16_f32 packs both output halves in 1 instr (RNE == f2bf)
// ---------------------------------------------------------------------------
__global__ void __launch_bounds__(256) k_msg(
    const unsigned short* __restrict__ bfrag, const unsigned short* __restrict__ afrag,
    const float* __restrict__ aproj, const float* __restrict__ w_comp,
    const float* __restrict__ B_w, const float* __restrict__ B_b,
    const int* __restrict__ e1, const unsigned short* __restrict__ e2,
    const unsigned short* __restrict__ init_bf, unsigned int* __restrict__ amsg32) {
    __shared__ float s_ap[NR * 32];                // 2048 B
    __shared__ float4 s_wc[NR];                    // 256 B
    const int tid = threadIdx.x;
    const int wave = tid >> 6;
    const int lane = tid & 63;
    const int m = lane & 15, quad = lane >> 4;
    const int t0 = (blockIdx.x * 4 + wave) * TPW;  // tile base, exact coverage
    // ---- stage small tables to LDS (once per block; STRIDED: 512 > 256 threads)
    for (int i = tid; i < NR * 32; i += 256) s_ap[i] = aproj[i];
    if (tid < NR) s_wc[tid] = ((const float4*)w_comp)[tid];
    // ---- hoisted fragments / constants (amortized over TPW tiles)
    const short8* bfp = (const short8*)bfrag;
    const short8* afp = (const short8*)afrag;
    short8 af0 = afp[0 * 64 + lane], af1 = afp[1 * 64 + lane];
    short8 af2 = afp[2 * 64 + lane], af3 = afp[3 * 64 + lane];
    short8 bf0 = bfp[0 * 64 + lane], bf1 = bfp[1 * 64 + lane];
    short8 bf2 = bfp[2 * 64 + lane], bf3 = bfp[3 * 64 + lane];
    short8 bf4 = bfp[4 * 64 + lane], bf5 = bfp[5 * 64 + lane];
    short8 bf6 = bfp[6 * 64 + lane], bf7 = bfp[7 * 64 + lane];
    const float bw0 = B_w[m], bw1 = B_w[m + 16], bb = B_b[0];
    const unsigned short* ibq = init_bf + quad * 8;
    // ---- all tile metadata upfront
    int ev[TPW]; int dv[TPW];
#pragma unroll
    for (int t = 0; t < TPW; t++) {
        ev[t] = e1[(t0 + t) * 16 + m];
        dv[t] = e2[(t0 + t) * 16 + m];
    }
    __syncthreads();                               // s_ap / s_wc ready
    // ---- gather pipeline (1-deep)
    short8 xa = *(const short8*)(ibq + (size_t)(ev[0] & 0xffff) * 32);
    short8 ya = *(const short8*)(ibq + (size_t)dv[0] * 32);
    const short8 z8 = {0, 0, 0, 0, 0, 0, 0, 0};
#pragma unroll
    for (int t = 0; t < TPW; t++) {
        short8 xan = z8, yan = z8;
        if (t + 1 < TPW) {                         // prefetch next tile's rows
            xan = *(const short8*)(ibq + (size_t)(ev[t + 1] & 0xffff) * 32);
            yan = *(const short8*)(ibq + (size_t)dv[t + 1] * 32);
        }
        const int ti = t0 + t;
        // per-edge metadata: edges quad*4+0..3, one quad-uniform int4 load
        const int4 evq = *(const int4*)(e1 + ti * 16 + quad * 4);
        int tr[4];
        tr[0] = (evq.x >> 16) & 15; tr[1] = (evq.y >> 16) & 15;
        tr[2] = (evq.z >> 16) & 15; tr[3] = (evq.w >> 16) & 15;
        float4 wcr[4];
#pragma unroll
        for (int r = 0; r < 4; r++) wcr[r] = s_wc[tr[r]];
        floatx4 z4 = {0.f, 0.f, 0.f, 0.f};
        // attention MFMAs
        floatx4 hc0 = __builtin_amdgcn_mfma_f32_16x16x32_bf16(xa, af0, z4, 0, 0, 0);
        hc0 = __builtin_amdgcn_mfma_f32_16x16x32_bf16(ya, af2, hc0, 0, 0, 0);
        floatx4 hc1 = __builtin_amdgcn_mfma_f32_16x16x32_bf16(xa, af1, z4, 0, 0, 0);
        hc1 = __builtin_amdgcn_mfma_f32_16x16x32_bf16(ya, af3, hc1, 0, 0, 0);
        // basis message MFMAs, folded per basis
        floatx4 m0 = z4, m1 = z4;
        {
            floatx4 zb0 = __builtin_amdgcn_mfma_f32_16x16x32_bf16(xa, bf0, z4, 0, 0, 0);
            floatx4 zb1 = __builtin_amdgcn_mfma_f32_16x16x32_bf16(xa, bf1, z4, 0, 0, 0);
#pragma unroll
            for (int r = 0; r < 4; r++) { m0[r] += wcr[r].x * zb0[r]; m1[r] += wcr[r].x * zb1[r]; }
        }
        {
            floatx4 zb0 = __builtin_amdgcn_mfma_f32_16x16x32_bf16(xa, bf2, z4, 0, 0, 0);
            floatx4 zb1 = __builtin_amdgcn_mfma_f32_16x16x32_bf16(xa, bf3, z4, 0, 0, 0);
#pragma unroll
            for (int r = 0; r < 4; r++) { m0[r] += wcr[r].y * zb0[r]; m1[r] += wcr[r].y * zb1[r]; }
        }
        {
            floatx4 zb0 = __builtin_amdgcn_mfma_f32_16x16x32_bf16(xa, bf4, z4, 0, 0, 0);
            floatx4 zb1 = __builtin_amdgcn_mfma_f32_16x16x32_bf16(xa, bf5, z4, 0, 0, 0);
#pragma unroll
            for (int r = 0; r < 4; r++) { m0[r] += wcr[r].z * zb0[r]; m1[r] += wcr[r].z * zb1[r]; }
        }
        {
            floatx4 zb0 = __builtin_amdgcn_mfma_f32_16x16x32_bf16(xa, bf6, z4, 0, 0, 0);
            floatx4 zb1 = __builtin_amdgcn_mfma_f32_16x16x32_bf16(xa, bf7, z4, 0, 0, 0);
#pragma unroll
            for (int r = 0; r < 4; r++) { m0[r] += wcr[r].w * zb0[r]; m1[r] += wcr[r].w * zb1[r]; }
        }
        // attention MLP + DPP 16-lane reduce (each quad is one DPP row)
        float part[4];
#pragma unroll
        for (int r = 0; r < 4; r++) {
            float p = fmaxf(hc0[r] + s_ap[tr[r] * 32 + m], 0.f) * bw0
                    + fmaxf(hc1[r] + s_ap[tr[r] * 32 + 16 + m], 0.f) * bw1;
            part[r] = rsum16(p);
        }
#pragma unroll
        for (int r = 0; r < 4; r++) {
            const int p = ti * 16 + quad * 4 + r;  // sequential: edges dst-sorted
            float a = 1.f / (1.f + __expf(-(part[r] + bb)));
            unsigned int pk;
            asm("v_cvt_pk_bf16_f32 %0, %1, %2" : "=v"(pk) : "v"(a * m0[r]), "v"(a * m1[r]));
            amsg32[(size_t)p * 16 + m] = pk;
        }
        xa = xan; ya = yan;
    }
}

// ---------------------------------------------------------------------------
// K6: dst-major aggregation + fused self-loop GEMM + ReLU (streaming amsg).
// amsg rows are packed u32: u32[m] = bf16(col m) | bf16(col m+16)<<16.
// Thread covering cols c0..c0+7 reads u32[(c0&8)..(c0&8)+7], lo/hi half.
// ---------------------------------------------------------------------------
__global__ void __launch_bounds__(256) k_agg(
    const int* __restrict__ row_off, const unsigned int* __restrict__ amsg32,
    const float* __restrict__ S, float* __restrict__ out) {
    int tid = threadIdx.x;
    int v = blockIdx.x * 64 + (tid >> 2);
    if (v >= NN) return;
    int c0 = (tid & 3) * 8;
    const int base = c0 & 8;
    const bool hi = c0 >= 16;
    float acc[8];
#pragma unroll
    for (int j = 0; j < 8; j++) acc[j] = 0.f;
    int p0 = row_off[v], p1 = row_off[v + 1];
    for (int p = p0; p < p1; p++) {
        const uint4* rp = (const uint4*)(amsg32 + (size_t)p * 16 + base);
        uint4 u0 = rp[0], u1 = rp[1];
        unsigned int uu[8] = {u0.x, u0.y, u0.z, u0.w, u1.x, u1.y, u1.z, u1.w};
#pragma unroll
        for (int j = 0; j < 8; j++) {
            unsigned int raw = hi ? (uu[j] & 0xffff0000u) : (uu[j] << 16);
            acc[j] += __uint_as_float(raw);
        }
    }
    float x[32];
    const float4* xp = (const float4*)(out + (size_t)v * 64);
#pragma unroll
    for (int q = 0; q < 8; q++) {
        float4 f = xp[q];
        x[4 * q] = f.x; x[4 * q + 1] = f.y; x[4 * q + 2] = f.z; x[4 * q + 3] = f.w;
    }
#pragma unroll
    for (int d = 0; d < 32; d++) {
        float xd = x[d];
#pragma unroll
        for (int j = 0; j < 8; j++) acc[j] += xd * S[d * 32 + c0 + j];
    }
    float4* op = (float4*)(out + (size_t)v * 64 + 32 + c0);
#pragma unroll
    for (int q = 0; q < 2; q++) {
        float4 f;
        f.x = fmaxf(acc[4 * q], 0.f);
        f.y = fmaxf(acc[4 * q + 1], 0.f);
        f.z = fmaxf(acc[4 * q + 2], 0.f);
        f.w = fmaxf(acc[4 * q + 3], 0.f);
        op[q] = f;
    }
}

extern "C" void kernel_launch(void* const* d_in, const int* in_sizes, int n_in,
                              void* d_out, int out_size, void* d_ws, size_t ws_size,
                              hipStream_t stream) {
    const float* feat      = (const float*)d_in[0];
    const float* embed     = (const float*)d_in[1];
    const float* transform = (const float*)d_in[2];
    const float* weight    = (const float*)d_in[3];
    const float* w_comp    = (const float*)d_in[4];
    const float* self_w    = (const float*)d_in[5];
    const float* A_w       = (const float*)d_in[6];
    const float* A_b       = (const float*)d_in[7];
    const float* B_w       = (const float*)d_in[8];
    const float* B_b       = (const float*)d_in[9];
    const float* attn_emb  = (const float*)d_in[10];
    const int*   idx       = (const int*)d_in[11];
    const int*   edge_src  = (const int*)d_in[12];
    const int*   edge_dst  = (const int*)d_in[13];
    const int*   edge_type = (const int*)d_in[14];
    float* out = (float*)d_out;

    // -------- workspace layout (~61 MB) --------
    char* ws = (char*)d_ws;
    unsigned int*   amsg32  = (unsigned int*)ws;                   // NE*64 B = 51,200,000
    int*            bpack   = (int*)ws;      // aliases amsg32[0 .. NE*4B): consumed by k_fine
                                             // BEFORE k_msg overwrites the region.
    unsigned short* init_bf = (unsigned short*)(ws + (size_t)NE * 64);               // 3,200,000 B
    unsigned short* bfrag   = (unsigned short*)((char*)init_bf + 3200000);           // 8,192 B
    unsigned short* afrag   = (unsigned short*)((char*)bfrag + 8192);                // 4,096 B
    float*          aproj   = (float*)((char*)afrag + 4096);                         // 2,048 B
    int* ip      = (int*)((char*)aproj + 2048);
    int* boff    = ip;            ip += NBC + 2;        // 783 used
    int* tot     = ip;            ip += 1024;
    int* cpb     = ip;            ip += ABLK * NBC;     // 200,192
    int* cpbx    = ip;            ip += ABLK * NBC;     // 200,192
    int* row_off = ip;            ip += NN + 1;
    int* e1      = ip;            ip += NE;             // 3,200,000 B
    unsigned short* e2 = (unsigned short*)ip;           // 1,600,000 B

    k_pre<<<516, 256, 0, stream>>>(feat, embed, transform, idx, weight,
                                   A_w, A_b, attn_emb, edge_dst,
                                   out, init_bf, bfrag, afrag, aproj, cpb);
    k_scan1<<<4, 256, 0, stream>>>(cpb, cpbx, tot);
    k_scan2<<<1, 1024, 0, stream>>>(tot, boff);
    k_scatA<<<ABLK, 1024, 0, stream>>>(edge_src, edge_dst, edge_type, cpbx, boff, bpack);
    k_fine<<<NBC, 256, 0, stream>>>(boff, bpack, row_off, e1, e2);
    k_msg<<<NTILE / (4 * TPW), 256, 0, stream>>>(bfrag, afrag, aproj, w_comp, B_w, B_b,
                                                 e1, e2, init_bf, amsg32);
    k_agg<<<(NN + 63) / 64, 256, 0, stream>>>(row_off, amsg32, self_w, out);
}